// Round 1
// baseline (74996.082 us; speedup 1.0000x reference)
//
#include <hip/hip_runtime.h>

typedef _Float16 f16;
typedef _Float16 f16x2 __attribute__((ext_vector_type(2)));
typedef _Float16 f16x8 __attribute__((ext_vector_type(8)));
typedef float    f32x4 __attribute__((ext_vector_type(4)));

#define TT   512
#define BB   64
#define DD   512
#define HH   1024
#define H2   2048
#define NR_  64
#define NH_  8
#define HD_  128
#define MROWS (TT*BB)      // 32768
#define RWG  64            // recurrence workgroups

// ---------------- prep kernels ----------------
__global__ void k_cvt(const float* __restrict__ s, f16* __restrict__ d, int n) {
  int i = blockIdx.x * blockDim.x + threadIdx.x;
  int st = gridDim.x * blockDim.x;
  for (; i < n; i += st) d[i] = (f16)s[i];
}

__global__ void k_scatter(const float* __restrict__ x, const int* __restrict__ idx,
                          f16* __restrict__ xpad, int total) {
  int i = blockIdx.x * blockDim.x + threadIdx.x;
  int st = gridDim.x * blockDim.x;
  int n = total * DD;
  for (; i < n; i += st) {
    int p = i >> 9;          // / DD
    int j = i & (DD - 1);
    xpad[(size_t)idx[p] * DD + j] = (f16)x[i];
  }
}

__global__ void k_inv(const int* __restrict__ idx, int* __restrict__ inv, int total) {
  int i = blockIdx.x * blockDim.x + threadIdx.x;
  if (i < total) inv[idx[i]] = i;
}

// ---------------- fp16 GEMM: C[m,n] = sum_k A[m,k]*Bw[n,k] + bias[n] ----------------
// 128x128 tile, BK=32, 4 waves, reg-staged LDS, 16x16x32 f16 MFMA.
__global__ __launch_bounds__(256)
void k_gemm(const f16* __restrict__ A, const f16* __restrict__ Bw,
            const float* __restrict__ bias, f16* __restrict__ C,
            int N, int K, int Mvalid) {
  __shared__ __align__(16) f16 As[128 * 32];
  __shared__ __align__(16) f16 Bs[128 * 32];
  const int tid  = threadIdx.x;
  const int lane = tid & 63;
  const int wave = tid >> 6;
  const int m0 = blockIdx.y * 128;
  const int n0 = blockIdx.x * 128;
  const int mw = (wave >> 1) * 64;
  const int nw = (wave & 1) * 64;
  const int NT = K >> 5;
  const int c0 = tid * 2;

  float4 pa[2], pb[2];
  auto fetch = [&](int kt) {
#pragma unroll
    for (int i = 0; i < 2; ++i) {
      int c = c0 + i;
      int row = c >> 2, kc = c & 3;
      pa[i] = *(const float4*)&A [(size_t)(m0 + row) * K + kt * 32 + kc * 8];
      pb[i] = *(const float4*)&Bw[(size_t)(n0 + row) * K + kt * 32 + kc * 8];
    }
  };

  f32x4 acc[4][4] = {};
  fetch(0);
  for (int kt = 0; kt < NT; ++kt) {
    __syncthreads();
#pragma unroll
    for (int i = 0; i < 2; ++i) {
      int c = c0 + i;
      *(float4*)&As[c * 8] = pa[i];
      *(float4*)&Bs[c * 8] = pb[i];
    }
    __syncthreads();
    if (kt + 1 < NT) fetch(kt + 1);
    f16x8 af[4], bf[4];
#pragma unroll
    for (int i = 0; i < 4; ++i) {
      af[i] = *(const f16x8*)&As[(mw + i * 16 + (lane & 15)) * 32 + (lane >> 4) * 8];
      bf[i] = *(const f16x8*)&Bs[(nw + i * 16 + (lane & 15)) * 32 + (lane >> 4) * 8];
    }
#pragma unroll
    for (int i = 0; i < 4; ++i)
#pragma unroll
      for (int j = 0; j < 4; ++j)
        acc[i][j] = __builtin_amdgcn_mfma_f32_16x16x32_f16(af[i], bf[j], acc[i][j], 0, 0, 0);
  }

#pragma unroll
  for (int j = 0; j < 4; ++j) {
    int col = n0 + nw + j * 16 + (lane & 15);
    float bv = bias[col];
#pragma unroll
    for (int i = 0; i < 4; ++i) {
#pragma unroll
      for (int r = 0; r < 4; ++r) {
        int row = m0 + mw + i * 16 + (lane >> 4) * 4 + r;
        if (row < Mvalid) C[(size_t)row * N + col] = (f16)(acc[i][j][r] + bv);
      }
    }
  }
}

// ---------------- device-wide barrier (monotone counter, all wgs co-resident) ----------------
__device__ inline void gbar(unsigned* cnt) {
  __syncthreads();                 // wg-local ops drained (compiler emits vmcnt(0) before barrier)
  if (threadIdx.x == 0) {
    unsigned old = __hip_atomic_fetch_add(cnt, 1u, __ATOMIC_ACQ_REL, __HIP_MEMORY_SCOPE_AGENT);
    unsigned target = (old / (unsigned)RWG + 1u) * (unsigned)RWG;
    while (__hip_atomic_load(cnt, __ATOMIC_RELAXED, __HIP_MEMORY_SCOPE_AGENT) < target)
      __builtin_amdgcn_s_sleep(2);
  }
  __syncthreads();
  __threadfence();                 // acquire: invalidate caches before reading peers' data
}

// ---------------- persistent recurrence kernel ----------------
// grid = 64 wgs x 512 threads. A-phase: wg=(ks 0..3, cs 0..15) computes partial
// fg[b, cs*128..+127] over k in [ks*256, ks*256+256) via MFMA with Wh slice in LDS.
// B-phase: wg=(head nh=wg>>3, batch octet wg&7), wave w -> one batch row.
__global__ __launch_bounds__(512, 2)
void k_rec(const f16* __restrict__ Wh16, const float* __restrict__ bh,
           const f16* __restrict__ v16,  const f16* __restrict__ x2fg,
           f16* __restrict__ hfrag, float* __restrict__ hcarry,
           float* __restrict__ P,
           f16* __restrict__ hs_out, float* __restrict__ out_packed,
           float* __restrict__ hn_out,
           const int* __restrict__ inv, const int* __restrict__ lgt,
           unsigned* __restrict__ cnt)
{
  __shared__ __align__(16) f16   Wlds[8 * 8 * 64 * 8];  // 64 KB [kk][nt][lane][8]
  __shared__ __align__(16) float fbuf[8][128];          // 4 KB
  __shared__ __align__(16) float abuf[8][64];           // 2 KB

  const int tid  = threadIdx.x;
  const int lane = tid & 63;
  const int wave = tid >> 6;
  const int wg   = blockIdx.x;
  const int ks   = wg & 3;
  const int cs   = wg >> 2;
  const int nh   = wg >> 3;
  const int b    = ((wg & 7) << 3) + wave;
  const int cf   = nh * HD_;

  // stage Wh slice into LDS in MFMA B-fragment layout
  for (int i = tid; i < 8 * 8 * 64; i += 512) {
    int kk  = i >> 9;
    int rem = i & 511;
    int nt  = rem >> 6;
    int ln  = rem & 63;
    int col = cs * 128 + nt * 16 + (ln & 15);
    int kg  = ks * 256 + kk * 32 + (ln >> 4) * 8;
    *(float4*)&Wlds[(size_t)i * 8] = *(const float4*)&Wh16[(size_t)col * HH + kg];
  }

  // register-resident role basis column (role = lane) and unbind basis column (d = lane / lane+64)
  f16x2 rt2[64];   // rt2[i] = (R[d=2i][lane], R[d=2i+1][lane])
  {
    const f16* vr = v16 + (size_t)lane * H2 + nh * 256;
#pragma unroll
    for (int i = 0; i < 64; ++i) rt2[i] = *(const f16x2*)&vr[2 * i];
  }
  f16x2 ud2[64];   // ud2[r] = (U[r][lane], U[r][lane+64])
#pragma unroll
  for (int r = 0; r < 64; ++r) {
    const f16* vu = v16 + (size_t)r * H2 + nh * 256 + 128;
    f16x2 t; t.x = vu[lane]; t.y = vu[lane + 64]; ud2[r] = t;
  }
  __syncthreads();

  const size_t hrow = (size_t)b * HH;
  for (int t = 0; t < TT; ++t) {
    // ---------- phase A: partial fg = h @ Wh^T (k-slice ks, col-slice cs) ----------
    f32x4 a0 = {0.f,0.f,0.f,0.f}, a1 = a0, a2 = a0, a3 = a0;
#pragma unroll
    for (int kk = 0; kk < 8; ++kk) {
      f16x8 bf = *(const f16x8*)&Wlds[((kk * 8 + wave) * 64 + lane) * 8];
      const f16* hf = hfrag + ((size_t)((ks * 8 + kk) * 4) * 64 + lane) * 8;
      f16x8 h0 = *(const f16x8*)&hf[0];
      f16x8 h1 = *(const f16x8*)&hf[512];
      f16x8 h2 = *(const f16x8*)&hf[1024];
      f16x8 h3 = *(const f16x8*)&hf[1536];
      a0 = __builtin_amdgcn_mfma_f32_16x16x32_f16(h0, bf, a0, 0, 0, 0);
      a1 = __builtin_amdgcn_mfma_f32_16x16x32_f16(h1, bf, a1, 0, 0, 0);
      a2 = __builtin_amdgcn_mfma_f32_16x16x32_f16(h2, bf, a2, 0, 0, 0);
      a3 = __builtin_amdgcn_mfma_f32_16x16x32_f16(h3, bf, a3, 0, 0, 0);
    }
    {
      const int col = cs * 128 + wave * 16 + (lane & 15);
      const int br  = (lane >> 4) * 4;
      float* Pb = P + (size_t)ks * BB * H2 + col;
#pragma unroll
      for (int r = 0; r < 4; ++r) {
        Pb[(size_t)(br + r)      * H2] = a0[r];
        Pb[(size_t)(16 + br + r) * H2] = a1[r];
        Pb[(size_t)(32 + br + r) * H2] = a2[r];
        Pb[(size_t)(48 + br + r) * H2] = a3[r];
      }
    }
    gbar(cnt);

    // ---------- phase B: reduce partials, softmax-bind, gated update ----------
    const size_t row = (size_t)t * BB + b;
    const int c0i = cf + lane, c1i = cf + lane + 64;
    float f0, f1, g0, g1;
    {
      const float* P0 = P + (size_t)b * H2;
      f0 = P0[c0i] + P0[BB*H2 + c0i] + P0[2*BB*H2 + c0i] + P0[3*BB*H2 + c0i];
      f1 = P0[c1i] + P0[BB*H2 + c1i] + P0[2*BB*H2 + c1i] + P0[3*BB*H2 + c1i];
      g0 = P0[HH + c0i] + P0[BB*H2 + HH + c0i] + P0[2*BB*H2 + HH + c0i] + P0[3*BB*H2 + HH + c0i];
      g1 = P0[HH + c1i] + P0[BB*H2 + HH + c1i] + P0[2*BB*H2 + HH + c1i] + P0[3*BB*H2 + HH + c1i];
      const f16* xr = x2fg + row * H2;
      f0 += bh[c0i] + (float)xr[c0i];
      f1 += bh[c1i] + (float)xr[c1i];
      g0 += bh[HH + c0i] + (float)xr[HH + c0i];
      g1 += bh[HH + c1i] + (float)xr[HH + c1i];
    }
    fbuf[wave][lane]      = f0;
    fbuf[wave][lane + 64] = f1;
    __syncthreads();
    // scores: lane = role; s = sum_d f[d] * R[d][role]
    float s = 0.f;
#pragma unroll
    for (int i = 0; i < 32; ++i) {
      float4 fv = *(const float4*)&fbuf[wave][4 * i];
      f16x2 ra = rt2[2 * i], rb = rt2[2 * i + 1];
      s = fmaf(fv.x, (float)ra.x, s);
      s = fmaf(fv.y, (float)ra.y, s);
      s = fmaf(fv.z, (float)rb.x, s);
      s = fmaf(fv.w, (float)rb.y, s);
    }
    float mx = s;
#pragma unroll
    for (int off = 32; off > 0; off >>= 1) mx = fmaxf(mx, __shfl_xor(mx, off));
    float e = expf(s - mx);
    float sum = e;
#pragma unroll
    for (int off = 32; off > 0; off >>= 1) sum += __shfl_xor(sum, off);
    abuf[wave][lane] = e / sum;
    __syncthreads();
    // bind: d = lane, lane+64; bd = sum_r attn[r] * U[r][d]
    float bd0 = 0.f, bd1 = 0.f;
#pragma unroll
    for (int i = 0; i < 16; ++i) {
      float4 av = *(const float4*)&abuf[wave][4 * i];
      f16x2 u0 = ud2[4*i], u1 = ud2[4*i+1], u2 = ud2[4*i+2], u3 = ud2[4*i+3];
      bd0 = fmaf(av.x, (float)u0.x, bd0); bd1 = fmaf(av.x, (float)u0.y, bd1);
      bd0 = fmaf(av.y, (float)u1.x, bd0); bd1 = fmaf(av.y, (float)u1.y, bd1);
      bd0 = fmaf(av.z, (float)u2.x, bd0); bd1 = fmaf(av.z, (float)u2.y, bd1);
      bd0 = fmaf(av.w, (float)u3.x, bd0); bd1 = fmaf(av.w, (float)u3.y, bd1);
    }
    float ho0 = hcarry[hrow + c0i], ho1 = hcarry[hrow + c1i];
    float gt0 = 1.f / (1.f + expf(-g0));
    float gt1 = 1.f / (1.f + expf(-g1));
    float hv0 = gt0 * tanhf(bd0) + (1.f - gt0) * ho0;
    float hv1 = gt1 * tanhf(bd1) + (1.f - gt1) * ho1;
    hcarry[hrow + c0i] = hv0;
    hcarry[hrow + c1i] = hv1;
    {
      int k = c0i;
      hfrag[(((size_t)(k >> 5) * 4 + (b >> 4)) * 64 + ((b & 15) + (((k >> 3) & 3) << 4))) * 8 + (k & 7)] = (f16)hv0;
      k = c1i;
      hfrag[(((size_t)(k >> 5) * 4 + (b >> 4)) * 64 + ((b & 15) + (((k >> 3) & 3) << 4))) * 8 + (k & 7)] = (f16)hv1;
    }
    if (hs_out) {
      hs_out[row * HH + c0i] = (f16)hv0;
      hs_out[row * HH + c1i] = (f16)hv1;
    }
    if (out_packed) {
      int p = inv[row];
      if (p >= 0) {
        out_packed[(size_t)p * HH + c0i] = hv0;
        out_packed[(size_t)p * HH + c1i] = hv1;
      }
    }
    if (lgt[b] == t + 1) {
      hn_out[hrow + c0i] = hv0;
      hn_out[hrow + c1i] = hv1;
    }
    gbar(cnt);
  }
}

// ---------------- host ----------------
extern "C" void kernel_launch(void* const* d_in, const int* in_sizes, int n_in,
                              void* d_out, int out_size, void* d_ws, size_t ws_size,
                              hipStream_t stream) {
  const float* x      = (const float*)d_in[0];
  const int*   idx    = (const int*)d_in[1];
  const int*   lgt    = (const int*)d_in[2];
  const float* basis0 = (const float*)d_in[3];
  const float* basis1 = (const float*)d_in[4];
  const float* Wx0 = (const float*)d_in[5];  const float* bx0 = (const float*)d_in[6];
  const float* Wh0 = (const float*)d_in[7];  const float* bh0 = (const float*)d_in[8];
  const float* Wv0 = (const float*)d_in[9];  const float* bv0 = (const float*)d_in[10];
  const float* Wx1 = (const float*)d_in[11]; const float* bx1 = (const float*)d_in[12];
  const float* Wh1 = (const float*)d_in[13]; const float* bh1 = (const float*)d_in[14];
  const float* Wv1 = (const float*)d_in[15]; const float* bv1 = (const float*)d_in[16];
  const int total = in_sizes[1];

  char* ws = (char*)d_ws;
  size_t off = 0;
  auto alloc = [&](size_t bytes) -> void* {
    void* p = (void*)(ws + off);
    off += (bytes + 255) & ~(size_t)255;
    return p;
  };

  unsigned* cnt  = (unsigned*)alloc(256);
  int*   inv     = (int*)alloc((size_t)MROWS * 4);
  f16*   xpad    = (f16*)alloc((size_t)MROWS * DD * 2);
  f16*   x2fg    = (f16*)alloc((size_t)MROWS * H2 * 2);
  f16*   hfrag   = (f16*)alloc((size_t)BB * HH * 2);
  float* hcarry  = (float*)alloc((size_t)BB * HH * 4);
  float* P       = (float*)alloc((size_t)4 * BB * H2 * 4);
  f16* Wx0h = (f16*)alloc((size_t)H2 * DD * 2);
  f16* Wh0h = (f16*)alloc((size_t)H2 * HH * 2);
  f16* Wv0h = (f16*)alloc((size_t)H2 * HH * 2);
  f16* Wx1h = (f16*)alloc((size_t)H2 * HH * 2);
  f16* Wh1h = (f16*)alloc((size_t)H2 * HH * 2);
  f16* Wv1h = (f16*)alloc((size_t)H2 * HH * 2);
  f16* bas0h = (f16*)alloc((size_t)128 * HH * 2);   // padded to 128 rows (GEMM tile)
  f16* bas1h = (f16*)alloc((size_t)128 * HH * 2);
  f16* v0h = (f16*)alloc((size_t)NR_ * H2 * 2);
  f16* v1h = (f16*)alloc((size_t)NR_ * H2 * 2);

  float* out = (float*)d_out;
  float* hn0 = out + (size_t)total * HH;
  float* hn1 = hn0 + (size_t)BB * HH;
  // layer-0 hidden sequence stashed as f16 inside d_out's packed region (64 MB < 80 MB),
  // dead before layer-1 overwrites packed outputs.
  f16* hs0 = (f16*)d_out;

  hipMemsetAsync(cnt, 0, 256, stream);
  hipMemsetAsync(inv, 0xFF, (size_t)MROWS * 4, stream);
  hipMemsetAsync(xpad, 0, (size_t)MROWS * DD * 2, stream);
  hipMemsetAsync(bas0h, 0, (size_t)128 * HH * 2, stream);
  hipMemsetAsync(bas1h, 0, (size_t)128 * HH * 2, stream);
  hipMemsetAsync(hfrag, 0, (size_t)BB * HH * 2, stream);
  hipMemsetAsync(hcarry, 0, (size_t)BB * HH * 4, stream);

  k_cvt<<<512, 256, 0, stream>>>(Wx0, Wx0h, H2 * DD);
  k_cvt<<<512, 256, 0, stream>>>(Wh0, Wh0h, H2 * HH);
  k_cvt<<<512, 256, 0, stream>>>(Wv0, Wv0h, H2 * HH);
  k_cvt<<<512, 256, 0, stream>>>(Wx1, Wx1h, H2 * HH);
  k_cvt<<<512, 256, 0, stream>>>(Wh1, Wh1h, H2 * HH);
  k_cvt<<<512, 256, 0, stream>>>(Wv1, Wv1h, H2 * HH);
  k_cvt<<<64, 256, 0, stream>>>(basis0, bas0h, NR_ * HH);
  k_cvt<<<64, 256, 0, stream>>>(basis1, bas1h, NR_ * HH);
  k_scatter<<<2048, 256, 0, stream>>>(x, idx, xpad, total);
  k_inv<<<(total + 255) / 256, 256, 0, stream>>>(idx, inv, total);

  dim3 gv(16, 1);
  k_gemm<<<gv, 256, 0, stream>>>(bas0h, Wv0h, bv0, v0h, H2, HH, NR_);
  k_gemm<<<gv, 256, 0, stream>>>(bas1h, Wv1h, bv1, v1h, H2, HH, NR_);

  dim3 gx(H2 / 128, MROWS / 128);
  k_gemm<<<gx, 256, 0, stream>>>(xpad, Wx0h, bx0, x2fg, H2, DD, MROWS);

  k_rec<<<RWG, 512, 0, stream>>>(Wh0h, bh0, v0h, x2fg, hfrag, hcarry, P,
                                 hs0, nullptr, hn0, inv, lgt, cnt);

  hipMemsetAsync(hfrag, 0, (size_t)BB * HH * 2, stream);
  hipMemsetAsync(hcarry, 0, (size_t)BB * HH * 4, stream);

  k_gemm<<<gx, 256, 0, stream>>>(hs0, Wx1h, bx1, x2fg, H2, HH, MROWS);

  k_rec<<<RWG, 512, 0, stream>>>(Wh1h, bh1, v1h, x2fg, hfrag, hcarry, P,
                                 nullptr, out, hn1, inv, lgt, cnt);
}

// Round 4
// 40647.540 us; speedup vs baseline: 1.8450x; 1.8450x over previous
//
#include <hip/hip_runtime.h>

typedef _Float16 f16;
typedef _Float16 f16x2 __attribute__((ext_vector_type(2)));
typedef _Float16 f16x8 __attribute__((ext_vector_type(8)));
typedef float    f32x4 __attribute__((ext_vector_type(4)));

#define TT   512
#define BB   64
#define DD   512
#define HH   1024
#define H2   2048
#define NR_  64
#define NH_  8
#define HD_  128
#define MROWS (TT*BB)      // 32768
#define RWG  64            // recurrence workgroups

// ---------------- prep kernels ----------------
__global__ void k_cvt(const float* __restrict__ s, f16* __restrict__ d, int n) {
  int i = blockIdx.x * blockDim.x + threadIdx.x;
  int st = gridDim.x * blockDim.x;
  for (; i < n; i += st) d[i] = (f16)s[i];
}

__global__ void k_scatter(const float* __restrict__ x, const int* __restrict__ idx,
                          f16* __restrict__ xpad, int total) {
  int i = blockIdx.x * blockDim.x + threadIdx.x;
  int st = gridDim.x * blockDim.x;
  int n = total * DD;
  for (; i < n; i += st) {
    int p = i >> 9;          // / DD
    int j = i & (DD - 1);
    xpad[(size_t)idx[p] * DD + j] = (f16)x[i];
  }
}

__global__ void k_inv(const int* __restrict__ idx, int* __restrict__ inv, int total) {
  int i = blockIdx.x * blockDim.x + threadIdx.x;
  if (i < total) inv[idx[i]] = i;
}

// ---------------- fp16 GEMM: C[m,n] = sum_k A[m,k]*Bw[n,k] + bias[n] ----------------
__global__ __launch_bounds__(256)
void k_gemm(const f16* __restrict__ A, const f16* __restrict__ Bw,
            const float* __restrict__ bias, f16* __restrict__ C,
            int N, int K, int Mvalid) {
  __shared__ __align__(16) f16 As[128 * 32];
  __shared__ __align__(16) f16 Bs[128 * 32];
  const int tid  = threadIdx.x;
  const int lane = tid & 63;
  const int wave = tid >> 6;
  const int m0 = blockIdx.y * 128;
  const int n0 = blockIdx.x * 128;
  const int mw = (wave >> 1) * 64;
  const int nw = (wave & 1) * 64;
  const int NT = K >> 5;
  const int c0 = tid * 2;

  float4 pa[2], pb[2];
  auto fetch = [&](int kt) {
#pragma unroll
    for (int i = 0; i < 2; ++i) {
      int c = c0 + i;
      int row = c >> 2, kc = c & 3;
      pa[i] = *(const float4*)&A [(size_t)(m0 + row) * K + kt * 32 + kc * 8];
      pb[i] = *(const float4*)&Bw[(size_t)(n0 + row) * K + kt * 32 + kc * 8];
    }
  };

  f32x4 acc[4][4] = {};
  fetch(0);
  for (int kt = 0; kt < NT; ++kt) {
    __syncthreads();
#pragma unroll
    for (int i = 0; i < 2; ++i) {
      int c = c0 + i;
      *(float4*)&As[c * 8] = pa[i];
      *(float4*)&Bs[c * 8] = pb[i];
    }
    __syncthreads();
    if (kt + 1 < NT) fetch(kt + 1);
    f16x8 af[4], bf[4];
#pragma unroll
    for (int i = 0; i < 4; ++i) {
      af[i] = *(const f16x8*)&As[(mw + i * 16 + (lane & 15)) * 32 + (lane >> 4) * 8];
      bf[i] = *(const f16x8*)&Bs[(nw + i * 16 + (lane & 15)) * 32 + (lane >> 4) * 8];
    }
#pragma unroll
    for (int i = 0; i < 4; ++i)
#pragma unroll
      for (int j = 0; j < 4; ++j)
        acc[i][j] = __builtin_amdgcn_mfma_f32_16x16x32_f16(af[i], bf[j], acc[i][j], 0, 0, 0);
  }

#pragma unroll
  for (int j = 0; j < 4; ++j) {
    int col = n0 + nw + j * 16 + (lane & 15);
    float bv = bias[col];
#pragma unroll
    for (int i = 0; i < 4; ++i) {
#pragma unroll
      for (int r = 0; r < 4; ++r) {
        int row = m0 + mw + i * 16 + (lane >> 4) * 4 + r;
        if (row < Mvalid) C[(size_t)row * N + col] = (f16)(acc[i][j][r] + bv);
      }
    }
  }
}

// ---------------- flag-array device barrier (no atomic RMW serialization) ----------------
__device__ inline void gbar(int* flags, int epoch) {
  __syncthreads();   // all wg threads' global writes drained (vmcnt0 before s_barrier)
  const int tid = threadIdx.x;
  if (tid == 0)
    __hip_atomic_store(&flags[blockIdx.x * 16], epoch, __ATOMIC_RELEASE, __HIP_MEMORY_SCOPE_AGENT);
  if (tid < RWG) {
    while (__hip_atomic_load(&flags[tid * 16], __ATOMIC_RELAXED, __HIP_MEMORY_SCOPE_AGENT) < epoch)
      __builtin_amdgcn_s_sleep(1);
  }
  __threadfence();   // acquire: order peers' released data before our reads
  __syncthreads();
}

// ---------------- persistent recurrence kernel ----------------
// 64 wgs x 512 thr. Phase A: wg = col-slice cs (32 cols, full K=1024);
// wave=(rt 0..3, ct 0..1): one complete 16x16 output tile (32 MFMA). No partials.
// Phase B: wave <-> (b=(wg&7)*8+wave, nh=wg>>3); h carried in registers.
__global__ __launch_bounds__(512, 2)
void k_rec(const f16* __restrict__ Wh16, const float* __restrict__ bh,
           const f16* __restrict__ v16,  const f16* __restrict__ x2fg,
           f16* __restrict__ hfrag, float* __restrict__ fgbuf,
           f16* __restrict__ hs_out, float* __restrict__ out_packed,
           float* __restrict__ hn_out,
           const int* __restrict__ inv, const int* __restrict__ lgt,
           int* __restrict__ flags, int epoch0)
{
  __shared__ __align__(16) f16   Wlds[32 * 2 * 64 * 8];  // 64 KB [kk][ct][lane][8]
  __shared__ __align__(16) float fbuf[8][128];           // 4 KB
  __shared__ __align__(16) float abuf[8][64];            // 2 KB

  const int tid  = threadIdx.x;
  const int lane = tid & 63;
  const int wave = tid >> 6;
  const int wg   = blockIdx.x;
  const int cs   = wg;                   // col-slice: cols cs*32 .. cs*32+32
  const int rt   = wave & 3;             // row tile 0..3 (all 64 batch rows)
  const int ct   = wave >> 2;            // col tile 0..1
  const int nh   = wg >> 3;
  const int b    = ((wg & 7) << 3) + wave;
  const int cf   = nh * HD_;

  // stage full-K Wh slice (32 cols) into LDS in MFMA B-fragment layout
  for (int i = tid; i < 32 * 2 * 64; i += 512) {
    int kk = i >> 7;
    int nt = (i >> 6) & 1;
    int ln = i & 63;
    int col = cs * 32 + nt * 16 + (ln & 15);
    int kg  = kk * 32 + (ln >> 4) * 8;
    *(float4*)&Wlds[(size_t)i * 8] = *(const float4*)&Wh16[(size_t)col * HH + kg];
  }

  // register-resident role basis (role = lane) and unbind basis (d = lane / lane+64)
  f16x2 rt2[64];
  {
    const f16* vr = v16 + (size_t)lane * H2 + nh * 256;
#pragma unroll
    for (int i = 0; i < 64; ++i) rt2[i] = *(const f16x2*)&vr[2 * i];
  }
  f16x2 ud2[64];
#pragma unroll
  for (int r = 0; r < 64; ++r) {
    const f16* vu = v16 + (size_t)r * H2 + nh * 256 + 128;
    f16x2 t; t.x = vu[lane]; t.y = vu[lane + 64]; ud2[r] = t;
  }
  __syncthreads();

  float ho0 = 0.f, ho1 = 0.f;   // register h-carry for (b, [cf+lane, cf+lane+64])
  int ep = epoch0;

  for (int t = 0; t < TT; ++t) {
    // ---------- phase A: complete fg tile (16x16 per wave, K=1024) ----------
    f32x4 acc = {0.f, 0.f, 0.f, 0.f};
#pragma unroll 4
    for (int kk = 0; kk < 32; ++kk) {
      f16x8 bf = *(const f16x8*)&Wlds[((kk * 2 + ct) * 64 + lane) * 8];
      f16x8 af = *(const f16x8*)&hfrag[((size_t)(kk * 4 + rt) * 64 + lane) * 8];
      acc = __builtin_amdgcn_mfma_f32_16x16x32_f16(af, bf, acc, 0, 0, 0);
    }
    {
      const int col = cs * 32 + ct * 16 + (lane & 15);
      const int r0  = rt * 16 + (lane >> 4) * 4;
#pragma unroll
      for (int r = 0; r < 4; ++r) fgbuf[(size_t)(r0 + r) * H2 + col] = acc[r];
    }
    gbar(flags, ++ep);

    // ---------- phase B: bias + x2fg, softmax-bind, gated update ----------
    const size_t row = (size_t)t * BB + b;
    const int c0i = cf + lane, c1i = cf + lane + 64;
    const float* fr = fgbuf + (size_t)b * H2;
    const f16*   xr = x2fg + row * H2;
    float f0 = fr[c0i]      + bh[c0i]      + (float)xr[c0i];
    float f1 = fr[c1i]      + bh[c1i]      + (float)xr[c1i];
    float g0 = fr[HH + c0i] + bh[HH + c0i] + (float)xr[HH + c0i];
    float g1 = fr[HH + c1i] + bh[HH + c1i] + (float)xr[HH + c1i];
    fbuf[wave][lane]      = f0;
    fbuf[wave][lane + 64] = f1;
    __syncthreads();
    // scores: lane = role
    float s = 0.f;
#pragma unroll
    for (int i = 0; i < 32; ++i) {
      float4 fv = *(const float4*)&fbuf[wave][4 * i];
      f16x2 ra = rt2[2 * i], rb = rt2[2 * i + 1];
      s = fmaf(fv.x, (float)ra.x, s);
      s = fmaf(fv.y, (float)ra.y, s);
      s = fmaf(fv.z, (float)rb.x, s);
      s = fmaf(fv.w, (float)rb.y, s);
    }
    float mx = s;
#pragma unroll
    for (int off = 32; off > 0; off >>= 1) mx = fmaxf(mx, __shfl_xor(mx, off));
    float e = expf(s - mx);
    float sum = e;
#pragma unroll
    for (int off = 32; off > 0; off >>= 1) sum += __shfl_xor(sum, off);
    abuf[wave][lane] = e / sum;
    __syncthreads();
    // bind: d = lane, lane+64
    float bd0 = 0.f, bd1 = 0.f;
#pragma unroll
    for (int i = 0; i < 16; ++i) {
      float4 av = *(const float4*)&abuf[wave][4 * i];
      f16x2 u0 = ud2[4*i], u1 = ud2[4*i+1], u2 = ud2[4*i+2], u3 = ud2[4*i+3];
      bd0 = fmaf(av.x, (float)u0.x, bd0); bd1 = fmaf(av.x, (float)u0.y, bd1);
      bd0 = fmaf(av.y, (float)u1.x, bd0); bd1 = fmaf(av.y, (float)u1.y, bd1);
      bd0 = fmaf(av.z, (float)u2.x, bd0); bd1 = fmaf(av.z, (float)u2.y, bd1);
      bd0 = fmaf(av.w, (float)u3.x, bd0); bd1 = fmaf(av.w, (float)u3.y, bd1);
    }
    float gt0 = 1.f / (1.f + expf(-g0));
    float gt1 = 1.f / (1.f + expf(-g1));
    float hv0 = gt0 * tanhf(bd0) + (1.f - gt0) * ho0;
    float hv1 = gt1 * tanhf(bd1) + (1.f - gt1) * ho1;
    ho0 = hv0; ho1 = hv1;
    {
      int k = c0i;
      hfrag[(((size_t)(k >> 5) * 4 + (b >> 4)) * 64 + ((b & 15) + (((k >> 3) & 3) << 4))) * 8 + (k & 7)] = (f16)hv0;
      k = c1i;
      hfrag[(((size_t)(k >> 5) * 4 + (b >> 4)) * 64 + ((b & 15) + (((k >> 3) & 3) << 4))) * 8 + (k & 7)] = (f16)hv1;
    }
    if (hs_out) {
      hs_out[row * HH + c0i] = (f16)hv0;
      hs_out[row * HH + c1i] = (f16)hv1;
    }
    if (out_packed) {
      int p = inv[row];
      if (p >= 0) {
        out_packed[(size_t)p * HH + c0i] = hv0;
        out_packed[(size_t)p * HH + c1i] = hv1;
      }
    }
    if (lgt[b] == t + 1) {
      hn_out[(size_t)b * HH + c0i] = hv0;
      hn_out[(size_t)b * HH + c1i] = hv1;
    }
    gbar(flags, ++ep);
  }
}

// ---------------- host ----------------
extern "C" void kernel_launch(void* const* d_in, const int* in_sizes, int n_in,
                              void* d_out, int out_size, void* d_ws, size_t ws_size,
                              hipStream_t stream) {
  const float* x      = (const float*)d_in[0];
  const int*   idx    = (const int*)d_in[1];
  const int*   lgt    = (const int*)d_in[2];
  const float* basis0 = (const float*)d_in[3];
  const float* basis1 = (const float*)d_in[4];
  const float* Wx0 = (const float*)d_in[5];  const float* bx0 = (const float*)d_in[6];
  const float* Wh0 = (const float*)d_in[7];  const float* bh0 = (const float*)d_in[8];
  const float* Wv0 = (const float*)d_in[9];  const float* bv0 = (const float*)d_in[10];
  const float* Wx1 = (const float*)d_in[11]; const float* bx1 = (const float*)d_in[12];
  const float* Wh1 = (const float*)d_in[13]; const float* bh1 = (const float*)d_in[14];
  const float* Wv1 = (const float*)d_in[15]; const float* bv1 = (const float*)d_in[16];
  const int total = in_sizes[1];

  char* ws = (char*)d_ws;
  size_t off = 0;
  auto alloc = [&](size_t bytes) -> void* {
    void* p = (void*)(ws + off);
    off += (bytes + 255) & ~(size_t)255;
    return p;
  };

  int*   flags   = (int*)alloc(RWG * 16 * 4);
  int*   inv     = (int*)alloc((size_t)MROWS * 4);
  f16*   xpad    = (f16*)alloc((size_t)MROWS * DD * 2);
  f16*   x2fg    = (f16*)alloc((size_t)MROWS * H2 * 2);
  f16*   hfrag   = (f16*)alloc((size_t)BB * HH * 2);
  float* fgbuf   = (float*)alloc((size_t)BB * H2 * 4);
  f16* Wx0h = (f16*)alloc((size_t)H2 * DD * 2);
  f16* Wh0h = (f16*)alloc((size_t)H2 * HH * 2);
  f16* Wv0h = (f16*)alloc((size_t)H2 * HH * 2);
  f16* Wx1h = (f16*)alloc((size_t)H2 * HH * 2);
  f16* Wh1h = (f16*)alloc((size_t)H2 * HH * 2);
  f16* Wv1h = (f16*)alloc((size_t)H2 * HH * 2);
  f16* bas0h = (f16*)alloc((size_t)128 * HH * 2);
  f16* bas1h = (f16*)alloc((size_t)128 * HH * 2);
  f16* v0h = (f16*)alloc((size_t)NR_ * H2 * 2);
  f16* v1h = (f16*)alloc((size_t)NR_ * H2 * 2);

  float* out = (float*)d_out;
  float* hn0 = out + (size_t)total * HH;
  float* hn1 = hn0 + (size_t)BB * HH;
  f16* hs0 = (f16*)d_out;   // layer-0 hidden stash (64 MB), dead before layer-1 output

  (void)hipMemsetAsync(flags, 0, RWG * 16 * 4, stream);
  (void)hipMemsetAsync(inv, 0xFF, (size_t)MROWS * 4, stream);
  (void)hipMemsetAsync(xpad, 0, (size_t)MROWS * DD * 2, stream);
  (void)hipMemsetAsync(bas0h, 0, (size_t)128 * HH * 2, stream);
  (void)hipMemsetAsync(bas1h, 0, (size_t)128 * HH * 2, stream);
  (void)hipMemsetAsync(hfrag, 0, (size_t)BB * HH * 2, stream);

  k_cvt<<<512, 256, 0, stream>>>(Wx0, Wx0h, H2 * DD);
  k_cvt<<<512, 256, 0, stream>>>(Wh0, Wh0h, H2 * HH);
  k_cvt<<<512, 256, 0, stream>>>(Wv0, Wv0h, H2 * HH);
  k_cvt<<<512, 256, 0, stream>>>(Wx1, Wx1h, H2 * HH);
  k_cvt<<<512, 256, 0, stream>>>(Wh1, Wh1h, H2 * HH);
  k_cvt<<<512, 256, 0, stream>>>(Wv1, Wv1h, H2 * HH);
  k_cvt<<<64, 256, 0, stream>>>(basis0, bas0h, NR_ * HH);
  k_cvt<<<64, 256, 0, stream>>>(basis1, bas1h, NR_ * HH);
  k_scatter<<<2048, 256, 0, stream>>>(x, idx, xpad, total);
  k_inv<<<(total + 255) / 256, 256, 0, stream>>>(idx, inv, total);

  dim3 gv(16, 1);
  k_gemm<<<gv, 256, 0, stream>>>(bas0h, Wv0h, bv0, v0h, H2, HH, NR_);
  k_gemm<<<gv, 256, 0, stream>>>(bas1h, Wv1h, bv1, v1h, H2, HH, NR_);

  dim3 gx(H2 / 128, MROWS / 128);
  k_gemm<<<gx, 256, 0, stream>>>(xpad, Wx0h, bx0, x2fg, H2, DD, MROWS);

  k_rec<<<RWG, 512, 0, stream>>>(Wh0h, bh0, v0h, x2fg, hfrag, fgbuf,
                                 hs0, nullptr, hn0, inv, lgt, flags, 0);

  (void)hipMemsetAsync(hfrag, 0, (size_t)BB * HH * 2, stream);

  k_gemm<<<gx, 256, 0, stream>>>(hs0, Wx1h, bx1, x2fg, H2, HH, MROWS);

  k_rec<<<RWG, 512, 0, stream>>>(Wh1h, bh1, v1h, x2fg, hfrag, fgbuf,
                                 nullptr, out, hn1, inv, lgt, flags, 2 * TT);
}

// Round 5
// 25147.327 us; speedup vs baseline: 2.9823x; 1.6164x over previous
//
#include <hip/hip_runtime.h>

typedef _Float16 f16;
typedef _Float16 f16x2 __attribute__((ext_vector_type(2)));
typedef _Float16 f16x4 __attribute__((ext_vector_type(4)));
typedef _Float16 f16x8 __attribute__((ext_vector_type(8)));
typedef float    f32x4 __attribute__((ext_vector_type(4)));

#define TT   512
#define BB   64
#define DD   512
#define HH   1024
#define H2   2048
#define NR_  64
#define NH_  8
#define HD_  128
#define MROWS (TT*BB)      // 32768
#define RWG  64            // recurrence workgroups

#define ALOAD32(p)   __hip_atomic_load((p),  __ATOMIC_RELAXED, __HIP_MEMORY_SCOPE_AGENT)
#define ALOAD64(p)   __hip_atomic_load((p),  __ATOMIC_RELAXED, __HIP_MEMORY_SCOPE_AGENT)
#define ASTORE(p,v)  __hip_atomic_store((p), (v), __ATOMIC_RELAXED, __HIP_MEMORY_SCOPE_AGENT)

// ---------------- prep kernels ----------------
__global__ void k_cvt(const float* __restrict__ s, f16* __restrict__ d, int n) {
  int i = blockIdx.x * blockDim.x + threadIdx.x;
  int st = gridDim.x * blockDim.x;
  for (; i < n; i += st) d[i] = (f16)s[i];
}

__global__ void k_scatter(const float* __restrict__ x, const int* __restrict__ idx,
                          f16* __restrict__ xpad, int total) {
  int i = blockIdx.x * blockDim.x + threadIdx.x;
  int st = gridDim.x * blockDim.x;
  int n = total * DD;
  for (; i < n; i += st) {
    int p = i >> 9;          // / DD
    int j = i & (DD - 1);
    xpad[(size_t)idx[p] * DD + j] = (f16)x[i];
  }
}

__global__ void k_inv(const int* __restrict__ idx, int* __restrict__ inv, int total) {
  int i = blockIdx.x * blockDim.x + threadIdx.x;
  if (i < total) inv[idx[i]] = i;
}

// ---------------- fp16 GEMM: C[m,n] = sum_k A[m,k]*Bw[n,k] + bias[n] ----------------
__global__ __launch_bounds__(256)
void k_gemm(const f16* __restrict__ A, const f16* __restrict__ Bw,
            const float* __restrict__ bias, f16* __restrict__ C,
            int N, int K, int Mvalid) {
  __shared__ __align__(16) f16 As[128 * 32];
  __shared__ __align__(16) f16 Bs[128 * 32];
  const int tid  = threadIdx.x;
  const int lane = tid & 63;
  const int wave = tid >> 6;
  const int m0 = blockIdx.y * 128;
  const int n0 = blockIdx.x * 128;
  const int mw = (wave >> 1) * 64;
  const int nw = (wave & 1) * 64;
  const int NT = K >> 5;
  const int c0 = tid * 2;

  float4 pa[2], pb[2];
  auto fetch = [&](int kt) {
#pragma unroll
    for (int i = 0; i < 2; ++i) {
      int c = c0 + i;
      int row = c >> 2, kc = c & 3;
      pa[i] = *(const float4*)&A [(size_t)(m0 + row) * K + kt * 32 + kc * 8];
      pb[i] = *(const float4*)&Bw[(size_t)(n0 + row) * K + kt * 32 + kc * 8];
    }
  };

  f32x4 acc[4][4] = {};
  fetch(0);
  for (int kt = 0; kt < NT; ++kt) {
    __syncthreads();
#pragma unroll
    for (int i = 0; i < 2; ++i) {
      int c = c0 + i;
      *(float4*)&As[c * 8] = pa[i];
      *(float4*)&Bs[c * 8] = pb[i];
    }
    __syncthreads();
    if (kt + 1 < NT) fetch(kt + 1);
    f16x8 af[4], bf[4];
#pragma unroll
    for (int i = 0; i < 4; ++i) {
      af[i] = *(const f16x8*)&As[(mw + i * 16 + (lane & 15)) * 32 + (lane >> 4) * 8];
      bf[i] = *(const f16x8*)&Bs[(nw + i * 16 + (lane & 15)) * 32 + (lane >> 4) * 8];
    }
#pragma unroll
    for (int i = 0; i < 4; ++i)
#pragma unroll
      for (int j = 0; j < 4; ++j)
        acc[i][j] = __builtin_amdgcn_mfma_f32_16x16x32_f16(af[i], bf[j], acc[i][j], 0, 0, 0);
  }

#pragma unroll
  for (int j = 0; j < 4; ++j) {
    int col = n0 + nw + j * 16 + (lane & 15);
    float bv = bias[col];
#pragma unroll
    for (int i = 0; i < 4; ++i) {
#pragma unroll
      for (int r = 0; r < 4; ++r) {
        int row = m0 + mw + i * 16 + (lane >> 4) * 4 + r;
        if (row < Mvalid) C[(size_t)row * N + col] = (f16)(acc[i][j][r] + bv);
      }
    }
  }
}

// ---------------- fence-free device barrier ----------------
// All cross-wg data uses agent-scope (L2-bypass, LLC-coherent) atomics, so no
// L2 writeback/invalidate is needed. __syncthreads() drains each wave's
// outstanding stores (implied vmcnt(0)) before the flag is published.
__device__ inline void gbar(int* flags, int epoch) {
  __syncthreads();
  const int tid = threadIdx.x;
  if (tid == 0) ASTORE(&flags[blockIdx.x * 16], epoch);
  if (tid < RWG) {
    while (ALOAD32(&flags[tid * 16]) < epoch) __builtin_amdgcn_s_sleep(1);
  }
  __syncthreads();
}

// ---------------- persistent recurrence kernel ----------------
// 64 wgs x 512 thr. Phase A: wg = col-slice cs (32 cols, full K=1024);
// wave=(rt 0..3, ct 0..1): one complete 16x16 output tile (32 MFMA).
// Phase B: wave <-> (b=(wg&7)*8+wave, nh=wg>>3); thread owns dims d0=2*lane, d0+1.
// h carried in registers; h/fg exchanged via LLC-coherent atomics only.
__global__ __launch_bounds__(512, 2)
void k_rec(const f16* __restrict__ Wh16, const float* __restrict__ bh,
           const f16* __restrict__ v16,  const f16* __restrict__ x2fg,
           f16* __restrict__ hfrag, float* __restrict__ fgbuf,
           f16* __restrict__ hs_out, float* __restrict__ out_packed,
           float* __restrict__ hn_out,
           const int* __restrict__ inv, const int* __restrict__ lgt,
           int* __restrict__ flags, int epoch0)
{
  __shared__ __align__(16) f16   Wlds[32 * 2 * 64 * 8];  // 64 KB [kk][ct][lane][8]
  __shared__ __align__(16) float fbuf[8][128];           // 4 KB (wave-private rows)
  __shared__ __align__(16) float abuf[8][64];            // 2 KB (wave-private rows)

  const int tid  = threadIdx.x;
  const int lane = tid & 63;
  const int wave = tid >> 6;
  const int wg   = blockIdx.x;
  const int cs   = wg;                   // col-slice: cols cs*32 .. cs*32+32
  const int rt   = wave & 3;             // row tile 0..3
  const int ct   = wave >> 2;            // col tile 0..1
  const int nh   = wg >> 3;
  const int b    = ((wg & 7) << 3) + wave;
  const int cf   = nh * HD_;

  // stage full-K Wh slice (32 cols) into LDS in MFMA B-fragment layout
  for (int i = tid; i < 32 * 2 * 64; i += 512) {
    int kk = i >> 7;
    int nt = (i >> 6) & 1;
    int ln = i & 63;
    int col = cs * 32 + nt * 16 + (ln & 15);
    int kg  = kk * 32 + (ln >> 4) * 8;
    *(float4*)&Wlds[(size_t)i * 8] = *(const float4*)&Wh16[(size_t)col * HH + kg];
  }

  // register-resident role basis (role = lane) and unbind basis (d = 2*lane, 2*lane+1)
  f16x2 rt2[64];
  {
    const f16* vr = v16 + (size_t)lane * H2 + nh * 256;
#pragma unroll
    for (int i = 0; i < 64; ++i) rt2[i] = *(const f16x2*)&vr[2 * i];
  }
  f16x2 ud2[64];
#pragma unroll
  for (int r = 0; r < 64; ++r) {
    const f16* vu = v16 + (size_t)r * H2 + nh * 256 + 128;
    ud2[r] = *(const f16x2*)&vu[2 * lane];
  }
  __syncthreads();

  const int d0 = cf + 2 * lane;          // this thread's two dims (adjacent)
  float ho0 = 0.f, ho1 = 0.f;            // register h-carry
  int ep = epoch0;
  const unsigned long long* hq = (const unsigned long long*)hfrag;

  for (int t = 0; t < TT; ++t) {
    // ---------- phase A: complete fg tile (16x16 per wave, K=1024) ----------
    f32x4 acc = {0.f, 0.f, 0.f, 0.f};
#pragma unroll 4
    for (int kk = 0; kk < 32; ++kk) {
      f16x8 bf = *(const f16x8*)&Wlds[((kk * 2 + ct) * 64 + lane) * 8];
      size_t qi = ((size_t)(kk * 4 + rt) * 64 + lane) * 2;
      unsigned long long lo = ALOAD64(&hq[qi]);
      unsigned long long hi = ALOAD64(&hq[qi + 1]);
      f16x8 af = __builtin_shufflevector(__builtin_bit_cast(f16x4, lo),
                                         __builtin_bit_cast(f16x4, hi),
                                         0, 1, 2, 3, 4, 5, 6, 7);
      acc = __builtin_amdgcn_mfma_f32_16x16x32_f16(af, bf, acc, 0, 0, 0);
    }
    {
      const int col = cs * 32 + ct * 16 + (lane & 15);
      const int r0  = rt * 16 + (lane >> 4) * 4;
#pragma unroll
      for (int r = 0; r < 4; ++r) ASTORE(&fgbuf[(size_t)(r0 + r) * H2 + col], acc[r]);
    }
    gbar(flags, ++ep);

    // ---------- phase B: bias + x2fg, softmax-bind, gated update ----------
    const size_t row = (size_t)t * BB + b;
    const f16* xr = x2fg + row * H2;
    float2 fv = __builtin_bit_cast(float2, ALOAD64((const unsigned long long*)&fgbuf[(size_t)b * H2 + d0]));
    float2 gv = __builtin_bit_cast(float2, ALOAD64((const unsigned long long*)&fgbuf[(size_t)b * H2 + HH + d0]));
    f16x2  xf = *(const f16x2*)&xr[d0];
    f16x2  xg = *(const f16x2*)&xr[HH + d0];
    float2 bf2 = *(const float2*)&bh[d0];
    float2 bg2 = *(const float2*)&bh[HH + d0];
    float f0 = fv.x + bf2.x + (float)xf.x;
    float f1 = fv.y + bf2.y + (float)xf.y;
    float g0 = gv.x + bg2.x + (float)xg.x;
    float g1 = gv.y + bg2.y + (float)xg.y;
    *(float2*)&fbuf[wave][2 * lane] = make_float2(f0, f1);   // wave-private row
    // scores: lane = role
    float s = 0.f;
#pragma unroll
    for (int i = 0; i < 32; ++i) {
      float4 fvv = *(const float4*)&fbuf[wave][4 * i];
      f16x2 ra = rt2[2 * i], rb = rt2[2 * i + 1];
      s = fmaf(fvv.x, (float)ra.x, s);
      s = fmaf(fvv.y, (float)ra.y, s);
      s = fmaf(fvv.z, (float)rb.x, s);
      s = fmaf(fvv.w, (float)rb.y, s);
    }
    float mx = s;
#pragma unroll
    for (int off = 32; off > 0; off >>= 1) mx = fmaxf(mx, __shfl_xor(mx, off));
    float e = expf(s - mx);
    float sum = e;
#pragma unroll
    for (int off = 32; off > 0; off >>= 1) sum += __shfl_xor(sum, off);
    abuf[wave][lane] = e / sum;
    // bind: d = d0, d0+1
    float bd0 = 0.f, bd1 = 0.f;
#pragma unroll
    for (int i = 0; i < 16; ++i) {
      float4 av = *(const float4*)&abuf[wave][4 * i];
      f16x2 u0 = ud2[4*i], u1 = ud2[4*i+1], u2 = ud2[4*i+2], u3 = ud2[4*i+3];
      bd0 = fmaf(av.x, (float)u0.x, bd0); bd1 = fmaf(av.x, (float)u0.y, bd1);
      bd0 = fmaf(av.y, (float)u1.x, bd0); bd1 = fmaf(av.y, (float)u1.y, bd1);
      bd0 = fmaf(av.z, (float)u2.x, bd0); bd1 = fmaf(av.z, (float)u2.y, bd1);
      bd0 = fmaf(av.w, (float)u3.x, bd0); bd1 = fmaf(av.w, (float)u3.y, bd1);
    }
    float gt0 = 1.f / (1.f + expf(-g0));
    float gt1 = 1.f / (1.f + expf(-g1));
    float hv0 = gt0 * tanhf(bd0) + (1.f - gt0) * ho0;
    float hv1 = gt1 * tanhf(bd1) + (1.f - gt1) * ho1;
    ho0 = hv0; ho1 = hv1;
    {
      // pack the two adjacent f16 h-values into one u32 LLC store (k0 even)
      const int k0 = d0;
      unsigned hp = (unsigned)__builtin_bit_cast(unsigned short, (f16)hv0)
                  | ((unsigned)__builtin_bit_cast(unsigned short, (f16)hv1) << 16);
      size_t ui = (((size_t)(k0 >> 5) * 4 + (b >> 4)) * 64
                   + ((b & 15) + (((k0 >> 3) & 3) << 4))) * 4 + ((k0 & 7) >> 1);
      ASTORE((unsigned*)hfrag + ui, hp);
    }
    if (hs_out) {
      f16x2 hp2; hp2.x = (f16)hv0; hp2.y = (f16)hv1;
      *(f16x2*)&hs_out[row * HH + d0] = hp2;
    }
    if (out_packed) {
      int p = inv[row];
      if (p >= 0) *(float2*)&out_packed[(size_t)p * HH + d0] = make_float2(hv0, hv1);
    }
    if (lgt[b] == t + 1) {
      *(float2*)&hn_out[(size_t)b * HH + d0] = make_float2(hv0, hv1);
    }
    gbar(flags, ++ep);
  }
}

// ---------------- host ----------------
extern "C" void kernel_launch(void* const* d_in, const int* in_sizes, int n_in,
                              void* d_out, int out_size, void* d_ws, size_t ws_size,
                              hipStream_t stream) {
  const float* x      = (const float*)d_in[0];
  const int*   idx    = (const int*)d_in[1];
  const int*   lgt    = (const int*)d_in[2];
  const float* basis0 = (const float*)d_in[3];
  const float* basis1 = (const float*)d_in[4];
  const float* Wx0 = (const float*)d_in[5];  const float* bx0 = (const float*)d_in[6];
  const float* Wh0 = (const float*)d_in[7];  const float* bh0 = (const float*)d_in[8];
  const float* Wv0 = (const float*)d_in[9];  const float* bv0 = (const float*)d_in[10];
  const float* Wx1 = (const float*)d_in[11]; const float* bx1 = (const float*)d_in[12];
  const float* Wh1 = (const float*)d_in[13]; const float* bh1 = (const float*)d_in[14];
  const float* Wv1 = (const float*)d_in[15]; const float* bv1 = (const float*)d_in[16];
  const int total = in_sizes[1];

  char* ws = (char*)d_ws;
  size_t off = 0;
  auto alloc = [&](size_t bytes) -> void* {
    void* p = (void*)(ws + off);
    off += (bytes + 255) & ~(size_t)255;
    return p;
  };

  int*   flags   = (int*)alloc(RWG * 16 * 4);
  int*   inv     = (int*)alloc((size_t)MROWS * 4);
  f16*   xpad    = (f16*)alloc((size_t)MROWS * DD * 2);
  f16*   x2fg    = (f16*)alloc((size_t)MROWS * H2 * 2);
  f16*   hfrag   = (f16*)alloc((size_t)BB * HH * 2);
  float* fgbuf   = (float*)alloc((size_t)BB * H2 * 4);
  f16* Wx0h = (f16*)alloc((size_t)H2 * DD * 2);
  f16* Wh0h = (f16*)alloc((size_t)H2 * HH * 2);
  f16* Wv0h = (f16*)alloc((size_t)H2 * HH * 2);
  f16* Wx1h = (f16*)alloc((size_t)H2 * HH * 2);
  f16* Wh1h = (f16*)alloc((size_t)H2 * HH * 2);
  f16* Wv1h = (f16*)alloc((size_t)H2 * HH * 2);
  f16* bas0h = (f16*)alloc((size_t)128 * HH * 2);
  f16* bas1h = (f16*)alloc((size_t)128 * HH * 2);
  f16* v0h = (f16*)alloc((size_t)NR_ * H2 * 2);
  f16* v1h = (f16*)alloc((size_t)NR_ * H2 * 2);

  float* out = (float*)d_out;
  float* hn0 = out + (size_t)total * HH;
  float* hn1 = hn0 + (size_t)BB * HH;
  f16* hs0 = (f16*)d_out;   // layer-0 hidden stash (64 MB), dead before layer-1 output

  (void)hipMemsetAsync(flags, 0, RWG * 16 * 4, stream);
  (void)hipMemsetAsync(inv, 0xFF, (size_t)MROWS * 4, stream);
  (void)hipMemsetAsync(xpad, 0, (size_t)MROWS * DD * 2, stream);
  (void)hipMemsetAsync(bas0h, 0, (size_t)128 * HH * 2, stream);
  (void)hipMemsetAsync(bas1h, 0, (size_t)128 * HH * 2, stream);
  (void)hipMemsetAsync(hfrag, 0, (size_t)BB * HH * 2, stream);

  k_cvt<<<512, 256, 0, stream>>>(Wx0, Wx0h, H2 * DD);
  k_cvt<<<512, 256, 0, stream>>>(Wh0, Wh0h, H2 * HH);
  k_cvt<<<512, 256, 0, stream>>>(Wv0, Wv0h, H2 * HH);
  k_cvt<<<512, 256, 0, stream>>>(Wx1, Wx1h, H2 * HH);
  k_cvt<<<512, 256, 0, stream>>>(Wh1, Wh1h, H2 * HH);
  k_cvt<<<512, 256, 0, stream>>>(Wv1, Wv1h, H2 * HH);
  k_cvt<<<64, 256, 0, stream>>>(basis0, bas0h, NR_ * HH);
  k_cvt<<<64, 256, 0, stream>>>(basis1, bas1h, NR_ * HH);
  k_scatter<<<2048, 256, 0, stream>>>(x, idx, xpad, total);
  k_inv<<<(total + 255) / 256, 256, 0, stream>>>(idx, inv, total);

  dim3 gv(16, 1);
  k_gemm<<<gv, 256, 0, stream>>>(bas0h, Wv0h, bv0, v0h, H2, HH, NR_);
  k_gemm<<<gv, 256, 0, stream>>>(bas1h, Wv1h, bv1, v1h, H2, HH, NR_);

  dim3 gx(H2 / 128, MROWS / 128);
  k_gemm<<<gx, 256, 0, stream>>>(xpad, Wx0h, bx0, x2fg, H2, DD, MROWS);

  k_rec<<<RWG, 512, 0, stream>>>(Wh0h, bh0, v0h, x2fg, hfrag, fgbuf,
                                 hs0, nullptr, hn0, inv, lgt, flags, 0);

  (void)hipMemsetAsync(hfrag, 0, (size_t)BB * HH * 2, stream);

  k_gemm<<<gx, 256, 0, stream>>>(hs0, Wx1h, bx1, x2fg, H2, HH, MROWS);

  k_rec<<<RWG, 512, 0, stream>>>(Wh1h, bh1, v1h, x2fg, hfrag, fgbuf,
                                 nullptr, out, hn1, inv, lgt, flags, 2 * TT);
}

// Round 6
// 19438.622 us; speedup vs baseline: 3.8581x; 1.2937x over previous
//
#include <hip/hip_runtime.h>

typedef _Float16 f16;
typedef _Float16 f16x2 __attribute__((ext_vector_type(2)));
typedef _Float16 f16x4 __attribute__((ext_vector_type(4)));
typedef _Float16 f16x8 __attribute__((ext_vector_type(8)));
typedef float    f32x4 __attribute__((ext_vector_type(4)));

#define TT   512
#define BB   64
#define DD   512
#define HH   1024
#define H2   2048
#define NR_  64
#define NH_  8
#define HD_  128
#define MROWS (TT*BB)      // 32768
#define RWG  64            // recurrence workgroups

#define ALOAD32(p)   __hip_atomic_load((p),  __ATOMIC_RELAXED, __HIP_MEMORY_SCOPE_AGENT)
#define ALOAD64(p)   __hip_atomic_load((p),  __ATOMIC_RELAXED, __HIP_MEMORY_SCOPE_AGENT)
#define ASTORE(p,v)  __hip_atomic_store((p), (v), __ATOMIC_RELAXED, __HIP_MEMORY_SCOPE_AGENT)

// ---------------- prep kernels ----------------
__global__ void k_cvt(const float* __restrict__ s, f16* __restrict__ d, int n) {
  int i = blockIdx.x * blockDim.x + threadIdx.x;
  int st = gridDim.x * blockDim.x;
  for (; i < n; i += st) d[i] = (f16)s[i];
}

__global__ void k_scatter(const float* __restrict__ x, const int* __restrict__ idx,
                          f16* __restrict__ xpad, int total) {
  int i = blockIdx.x * blockDim.x + threadIdx.x;
  int st = gridDim.x * blockDim.x;
  int n = total * DD;
  for (; i < n; i += st) {
    int p = i >> 9;          // / DD
    int j = i & (DD - 1);
    xpad[(size_t)idx[p] * DD + j] = (f16)x[i];
  }
}

__global__ void k_inv(const int* __restrict__ idx, int* __restrict__ inv, int total) {
  int i = blockIdx.x * blockDim.x + threadIdx.x;
  if (i < total) inv[idx[i]] = i;
}

// ---------------- fp16 GEMM: C[m,n] = sum_k A[m,k]*Bw[n,k] + bias[n] ----------------
__global__ __launch_bounds__(256)
void k_gemm(const f16* __restrict__ A, const f16* __restrict__ Bw,
            const float* __restrict__ bias, f16* __restrict__ C,
            int N, int K, int Mvalid) {
  __shared__ __align__(16) f16 As[128 * 32];
  __shared__ __align__(16) f16 Bs[128 * 32];
  const int tid  = threadIdx.x;
  const int lane = tid & 63;
  const int wave = tid >> 6;
  const int m0 = blockIdx.y * 128;
  const int n0 = blockIdx.x * 128;
  const int mw = (wave >> 1) * 64;
  const int nw = (wave & 1) * 64;
  const int NT = K >> 5;
  const int c0 = tid * 2;

  float4 pa[2], pb[2];
  auto fetch = [&](int kt) {
#pragma unroll
    for (int i = 0; i < 2; ++i) {
      int c = c0 + i;
      int row = c >> 2, kc = c & 3;
      pa[i] = *(const float4*)&A [(size_t)(m0 + row) * K + kt * 32 + kc * 8];
      pb[i] = *(const float4*)&Bw[(size_t)(n0 + row) * K + kt * 32 + kc * 8];
    }
  };

  f32x4 acc[4][4] = {};
  fetch(0);
  for (int kt = 0; kt < NT; ++kt) {
    __syncthreads();
#pragma unroll
    for (int i = 0; i < 2; ++i) {
      int c = c0 + i;
      *(float4*)&As[c * 8] = pa[i];
      *(float4*)&Bs[c * 8] = pb[i];
    }
    __syncthreads();
    if (kt + 1 < NT) fetch(kt + 1);
    f16x8 af[4], bf[4];
#pragma unroll
    for (int i = 0; i < 4; ++i) {
      af[i] = *(const f16x8*)&As[(mw + i * 16 + (lane & 15)) * 32 + (lane >> 4) * 8];
      bf[i] = *(const f16x8*)&Bs[(nw + i * 16 + (lane & 15)) * 32 + (lane >> 4) * 8];
    }
#pragma unroll
    for (int i = 0; i < 4; ++i)
#pragma unroll
      for (int j = 0; j < 4; ++j)
        acc[i][j] = __builtin_amdgcn_mfma_f32_16x16x32_f16(af[i], bf[j], acc[i][j], 0, 0, 0);
  }

#pragma unroll
  for (int j = 0; j < 4; ++j) {
    int col = n0 + nw + j * 16 + (lane & 15);
    float bv = bias[col];
#pragma unroll
    for (int i = 0; i < 4; ++i) {
#pragma unroll
      for (int r = 0; r < 4; ++r) {
        int row = m0 + mw + i * 16 + (lane >> 4) * 4 + r;
        if (row < Mvalid) C[(size_t)row * N + col] = (f16)(acc[i][j][r] + bv);
      }
    }
  }
}

// ---------------- fence-free device barrier (packed flags, coalesced poll) ----------------
__device__ inline void gbar(int* flags, int epoch) {
  __syncthreads();   // drains each wave's outstanding global stores (vmcnt 0) before s_barrier
  const int tid = threadIdx.x;
  if (tid == 0) ASTORE(&flags[blockIdx.x], epoch);
  if (tid < RWG) {
    while (ALOAD32(&flags[tid]) < epoch) __builtin_amdgcn_s_sleep(1);
  }
  __syncthreads();
}

// ---------------- persistent recurrence kernel ----------------
// 64 wgs x 512 thr. Phase A: wg = col-slice cs (32 cols, full K=1024);
// wave=(rt 0..3, ct 0..1): one complete 16x16 output tile (32 MFMA, batched h loads).
// Phase B: wave <-> (b=(wg&7)*8+wave, nh=wg>>3); thread owns dims d0=2*lane, d0+1.
// Role/unbind bases live in LDS; h carried in registers; h/fg via LLC atomics only.
__global__ __launch_bounds__(512, 2)
void k_rec(const f16* __restrict__ Wh16, const float* __restrict__ bh,
           const f16* __restrict__ v16,  const f16* __restrict__ x2fg,
           f16* __restrict__ hfrag, float* __restrict__ fgbuf,
           f16* __restrict__ hs_out, float* __restrict__ out_packed,
           float* __restrict__ hn_out,
           const int* __restrict__ inv, const int* __restrict__ lgt,
           int* __restrict__ flags, int epoch0)
{
  __shared__ __align__(16) f16   Wlds[32 * 2 * 64 * 8];  // 64 KB [kk][ct][lane][8]
  __shared__ __align__(16) f16x4 Rq[32 * 64];            // 16 KB: Rq[i][role] = R coeffs d=4i..4i+3
  __shared__ __align__(16) f16x4 Uq[16 * 2 * 64];        // 16 KB: Uq[i][half][l] = U roles (4i+2h,+1) dims (2l,2l+1)
  __shared__ __align__(16) float fbuf[8][128];           // 4 KB (wave-private rows)
  __shared__ __align__(16) float abuf[8][64];            // 2 KB (wave-private rows)

  const int tid  = threadIdx.x;
  const int lane = tid & 63;
  const int wave = tid >> 6;
  const int wg   = blockIdx.x;
  const int cs   = wg;                   // col-slice: cols cs*32 .. cs*32+32
  const int rt   = wave & 3;             // row tile 0..3
  const int ct   = wave >> 2;            // col tile 0..1
  const int nh   = wg >> 3;
  const int b    = ((wg & 7) << 3) + wave;
  const int cf   = nh * HD_;

  // stage full-K Wh slice (32 cols) into LDS in MFMA B-fragment layout
  for (int i = tid; i < 32 * 2 * 64; i += 512) {
    int kk = i >> 7;
    int nt = (i >> 6) & 1;
    int ln = i & 63;
    int col = cs * 32 + nt * 16 + (ln & 15);
    int kg  = kk * 32 + (ln >> 4) * 8;
    *(float4*)&Wlds[(size_t)i * 8] = *(const float4*)&Wh16[(size_t)col * HH + kg];
  }
  // role basis -> LDS: Rq[i*64+role] = v16[role*H2 + nh*256 + 4i .. +3]
  for (int e = tid; e < 32 * 64; e += 512) {
    int i = e >> 6, role = e & 63;
    Rq[e] = *(const f16x4*)&v16[(size_t)role * H2 + nh * 256 + 4 * i];
  }
  // unbind basis -> LDS: Uq[(i*2+half)*64+l] = (U[r0][2l],U[r0][2l+1],U[r0+1][2l],U[r0+1][2l+1])
  for (int e = tid; e < 16 * 2 * 64; e += 512) {
    int i = e >> 7, half = (e >> 6) & 1, l = e & 63;
    int r0 = 4 * i + 2 * half;
    const f16* u0 = &v16[(size_t)r0 * H2 + nh * 256 + 128 + 2 * l];
    const f16* u1 = &v16[(size_t)(r0 + 1) * H2 + nh * 256 + 128 + 2 * l];
    f16x4 tv; tv.x = u0[0]; tv.y = u0[1]; tv.z = u1[0]; tv.w = u1[1];
    Uq[e] = tv;
  }
  __syncthreads();

  const int d0 = cf + 2 * lane;          // this thread's two dims (adjacent)
  const float2 bf2 = *(const float2*)&bh[d0];        // loop-invariant biases
  const float2 bg2 = *(const float2*)&bh[HH + d0];
  const int lb = lgt[b];
  float ho0 = 0.f, ho1 = 0.f;            // register h-carry
  int ep = epoch0;
  const unsigned long long* hq = (const unsigned long long*)hfrag;

  for (int t = 0; t < TT; ++t) {
    const size_t row = (size_t)t * BB + b;
    // ---- prefetch phase-B inputs (normal cached loads, consumed after barrier 1) ----
    const f16* xr = x2fg + row * H2;
    f16x2 xf = *(const f16x2*)&xr[d0];
    f16x2 xg = *(const f16x2*)&xr[HH + d0];
    int   p  = inv[row];

    // ---------- phase A: complete fg tile (16x16 per wave, K=1024) ----------
    f32x4 accA = {0.f, 0.f, 0.f, 0.f}, accB = accA;
#pragma unroll
    for (int half = 0; half < 2; ++half) {
      unsigned long long hlo[16], hhi[16];
#pragma unroll
      for (int j = 0; j < 16; ++j) {
        int kk = half * 16 + j;
        size_t qi = ((size_t)(kk * 4 + rt) * 64 + lane) * 2;
        hlo[j] = ALOAD64(&hq[qi]);
        hhi[j] = ALOAD64(&hq[qi + 1]);
      }
#pragma unroll
      for (int j = 0; j < 16; ++j) {
        int kk = half * 16 + j;
        f16x8 bf = *(const f16x8*)&Wlds[((kk * 2 + ct) * 64 + lane) * 8];
        f16x8 af = __builtin_shufflevector(__builtin_bit_cast(f16x4, hlo[j]),
                                           __builtin_bit_cast(f16x4, hhi[j]),
                                           0, 1, 2, 3, 4, 5, 6, 7);
        if (j & 1) accB = __builtin_amdgcn_mfma_f32_16x16x32_f16(af, bf, accB, 0, 0, 0);
        else       accA = __builtin_amdgcn_mfma_f32_16x16x32_f16(af, bf, accA, 0, 0, 0);
      }
    }
    f32x4 acc = accA + accB;
    {
      const int col = cs * 32 + ct * 16 + (lane & 15);
      const int r0  = rt * 16 + (lane >> 4) * 4;
#pragma unroll
      for (int r = 0; r < 4; ++r) ASTORE(&fgbuf[(size_t)(r0 + r) * H2 + col], acc[r]);
    }
    gbar(flags, ++ep);

    // ---------- phase B: bias + x2fg, softmax-bind, gated update ----------
    float2 fv = __builtin_bit_cast(float2, ALOAD64((const unsigned long long*)&fgbuf[(size_t)b * H2 + d0]));
    float2 gv = __builtin_bit_cast(float2, ALOAD64((const unsigned long long*)&fgbuf[(size_t)b * H2 + HH + d0]));
    float f0 = fv.x + bf2.x + (float)xf.x;
    float f1 = fv.y + bf2.y + (float)xf.y;
    float g0 = gv.x + bg2.x + (float)xg.x;
    float g1 = gv.y + bg2.y + (float)xg.y;
    *(float2*)&fbuf[wave][2 * lane] = make_float2(f0, f1);   // wave-private row (DS in-order per wave)
    // scores: lane = role
    float s = 0.f;
#pragma unroll
    for (int i = 0; i < 32; ++i) {
      float4 fvv = *(const float4*)&fbuf[wave][4 * i];
      f16x4 rv = Rq[i * 64 + lane];
      s = fmaf(fvv.x, (float)rv.x, s);
      s = fmaf(fvv.y, (float)rv.y, s);
      s = fmaf(fvv.z, (float)rv.z, s);
      s = fmaf(fvv.w, (float)rv.w, s);
    }
    float mx = s;
#pragma unroll
    for (int off = 32; off > 0; off >>= 1) mx = fmaxf(mx, __shfl_xor(mx, off));
    float e = expf(s - mx);
    float sum = e;
#pragma unroll
    for (int off = 32; off > 0; off >>= 1) sum += __shfl_xor(sum, off);
    abuf[wave][lane] = e / sum;
    // bind: d = d0, d0+1
    float bd0 = 0.f, bd1 = 0.f;
#pragma unroll
    for (int i = 0; i < 16; ++i) {
      float4 av = *(const float4*)&abuf[wave][4 * i];
      f16x4 u01 = Uq[(i * 2 + 0) * 64 + lane];
      f16x4 u23 = Uq[(i * 2 + 1) * 64 + lane];
      bd0 = fmaf(av.x, (float)u01.x, bd0); bd1 = fmaf(av.x, (float)u01.y, bd1);
      bd0 = fmaf(av.y, (float)u01.z, bd0); bd1 = fmaf(av.y, (float)u01.w, bd1);
      bd0 = fmaf(av.z, (float)u23.x, bd0); bd1 = fmaf(av.z, (float)u23.y, bd1);
      bd0 = fmaf(av.w, (float)u23.z, bd0); bd1 = fmaf(av.w, (float)u23.w, bd1);
    }
    float gt0 = 1.f / (1.f + expf(-g0));
    float gt1 = 1.f / (1.f + expf(-g1));
    float hv0 = gt0 * tanhf(bd0) + (1.f - gt0) * ho0;
    float hv1 = gt1 * tanhf(bd1) + (1.f - gt1) * ho1;
    ho0 = hv0; ho1 = hv1;
    {
      // pack the two adjacent f16 h-values into one u32 LLC store (k0 even)
      const int k0 = d0;
      unsigned hp = (unsigned)__builtin_bit_cast(unsigned short, (f16)hv0)
                  | ((unsigned)__builtin_bit_cast(unsigned short, (f16)hv1) << 16);
      size_t ui = (((size_t)(k0 >> 5) * 4 + (b >> 4)) * 64
                   + ((b & 15) + (((k0 >> 3) & 3) << 4))) * 4 + ((k0 & 7) >> 1);
      ASTORE((unsigned*)hfrag + ui, hp);
    }
    gbar(flags, ++ep);

    // ---- deferred output writes: overlap with next iteration's phase A ----
    if (hs_out) {
      f16x2 hp2; hp2.x = (f16)ho0; hp2.y = (f16)ho1;
      *(f16x2*)&hs_out[row * HH + d0] = hp2;
    }
    if (out_packed && p >= 0) {
      *(float2*)&out_packed[(size_t)p * HH + d0] = make_float2(ho0, ho1);
    }
    if (lb == t + 1) {
      *(float2*)&hn_out[(size_t)b * HH + d0] = make_float2(ho0, ho1);
    }
  }
}

// ---------------- host ----------------
extern "C" void kernel_launch(void* const* d_in, const int* in_sizes, int n_in,
                              void* d_out, int out_size, void* d_ws, size_t ws_size,
                              hipStream_t stream) {
  const float* x      = (const float*)d_in[0];
  const int*   idx    = (const int*)d_in[1];
  const int*   lgt    = (const int*)d_in[2];
  const float* basis0 = (const float*)d_in[3];
  const float* basis1 = (const float*)d_in[4];
  const float* Wx0 = (const float*)d_in[5];  const float* bx0 = (const float*)d_in[6];
  const float* Wh0 = (const float*)d_in[7];  const float* bh0 = (const float*)d_in[8];
  const float* Wv0 = (const float*)d_in[9];  const float* bv0 = (const float*)d_in[10];
  const float* Wx1 = (const float*)d_in[11]; const float* bx1 = (const float*)d_in[12];
  const float* Wh1 = (const float*)d_in[13]; const float* bh1 = (const float*)d_in[14];
  const float* Wv1 = (const float*)d_in[15]; const float* bv1 = (const float*)d_in[16];
  const int total = in_sizes[1];

  char* ws = (char*)d_ws;
  size_t off = 0;
  auto alloc = [&](size_t bytes) -> void* {
    void* p = (void*)(ws + off);
    off += (bytes + 255) & ~(size_t)255;
    return p;
  };

  int*   flags   = (int*)alloc(RWG * 4);
  int*   inv     = (int*)alloc((size_t)MROWS * 4);
  f16*   xpad    = (f16*)alloc((size_t)MROWS * DD * 2);
  f16*   x2fg    = (f16*)alloc((size_t)MROWS * H2 * 2);
  f16*   hfrag   = (f16*)alloc((size_t)BB * HH * 2);
  float* fgbuf   = (float*)alloc((size_t)BB * H2 * 4);
  f16* Wx0h = (f16*)alloc((size_t)H2 * DD * 2);
  f16* Wh0h = (f16*)alloc((size_t)H2 * HH * 2);
  f16* Wv0h = (f16*)alloc((size_t)H2 * HH * 2);
  f16* Wx1h = (f16*)alloc((size_t)H2 * HH * 2);
  f16* Wh1h = (f16*)alloc((size_t)H2 * HH * 2);
  f16* Wv1h = (f16*)alloc((size_t)H2 * HH * 2);
  f16* bas0h = (f16*)alloc((size_t)128 * HH * 2);
  f16* bas1h = (f16*)alloc((size_t)128 * HH * 2);
  f16* v0h = (f16*)alloc((size_t)NR_ * H2 * 2);
  f16* v1h = (f16*)alloc((size_t)NR_ * H2 * 2);

  float* out = (float*)d_out;
  float* hn0 = out + (size_t)total * HH;
  float* hn1 = hn0 + (size_t)BB * HH;
  f16* hs0 = (f16*)d_out;   // layer-0 hidden stash (64 MB), dead before layer-1 output

  (void)hipMemsetAsync(flags, 0, RWG * 4, stream);
  (void)hipMemsetAsync(inv, 0xFF, (size_t)MROWS * 4, stream);
  (void)hipMemsetAsync(xpad, 0, (size_t)MROWS * DD * 2, stream);
  (void)hipMemsetAsync(bas0h, 0, (size_t)128 * HH * 2, stream);
  (void)hipMemsetAsync(bas1h, 0, (size_t)128 * HH * 2, stream);
  (void)hipMemsetAsync(hfrag, 0, (size_t)BB * HH * 2, stream);

  k_cvt<<<512, 256, 0, stream>>>(Wx0, Wx0h, H2 * DD);
  k_cvt<<<512, 256, 0, stream>>>(Wh0, Wh0h, H2 * HH);
  k_cvt<<<512, 256, 0, stream>>>(Wv0, Wv0h, H2 * HH);
  k_cvt<<<512, 256, 0, stream>>>(Wx1, Wx1h, H2 * HH);
  k_cvt<<<512, 256, 0, stream>>>(Wh1, Wh1h, H2 * HH);
  k_cvt<<<512, 256, 0, stream>>>(Wv1, Wv1h, H2 * HH);
  k_cvt<<<64, 256, 0, stream>>>(basis0, bas0h, NR_ * HH);
  k_cvt<<<64, 256, 0, stream>>>(basis1, bas1h, NR_ * HH);
  k_scatter<<<2048, 256, 0, stream>>>(x, idx, xpad, total);
  k_inv<<<(total + 255) / 256, 256, 0, stream>>>(idx, inv, total);

  dim3 gv(16, 1);
  k_gemm<<<gv, 256, 0, stream>>>(bas0h, Wv0h, bv0, v0h, H2, HH, NR_);
  k_gemm<<<gv, 256, 0, stream>>>(bas1h, Wv1h, bv1, v1h, H2, HH, NR_);

  dim3 gx(H2 / 128, MROWS / 128);
  k_gemm<<<gx, 256, 0, stream>>>(xpad, Wx0h, bx0, x2fg, H2, DD, MROWS);

  k_rec<<<RWG, 512, 0, stream>>>(Wh0h, bh0, v0h, x2fg, hfrag, fgbuf,
                                 hs0, nullptr, hn0, inv, lgt, flags, 0);

  (void)hipMemsetAsync(hfrag, 0, (size_t)BB * HH * 2, stream);

  k_gemm<<<gx, 256, 0, stream>>>(hs0, Wx1h, bx1, x2fg, H2, HH, MROWS);

  k_rec<<<RWG, 512, 0, stream>>>(Wh1h, bh1, v1h, x2fg, hfrag, fgbuf,
                                 nullptr, out, hn1, inv, lgt, flags, 2 * TT);
}

// Round 7
// 14435.753 us; speedup vs baseline: 5.1952x; 1.3466x over previous
//
#include <hip/hip_runtime.h>

typedef _Float16 f16;
typedef _Float16 f16x2 __attribute__((ext_vector_type(2)));
typedef _Float16 f16x4 __attribute__((ext_vector_type(4)));
typedef _Float16 f16x8 __attribute__((ext_vector_type(8)));
typedef float    f32x4 __attribute__((ext_vector_type(4)));

#define TT   512
#define BB   64
#define DD   512
#define HH   1024
#define H2   2048
#define NR_  64
#define NH_  8
#define HD_  128
#define MROWS (TT*BB)      // 32768
#define RWG  64            // recurrence workgroups

#define ALOAD32(p)   __hip_atomic_load((p),  __ATOMIC_RELAXED, __HIP_MEMORY_SCOPE_AGENT)
#define ALOAD64(p)   __hip_atomic_load((p),  __ATOMIC_RELAXED, __HIP_MEMORY_SCOPE_AGENT)
#define ASTORE(p,v)  __hip_atomic_store((p), (v), __ATOMIC_RELAXED, __HIP_MEMORY_SCOPE_AGENT)

// ---------------- prep kernels ----------------
__global__ void k_cvt(const float* __restrict__ s, f16* __restrict__ d, int n) {
  int i = blockIdx.x * blockDim.x + threadIdx.x;
  int st = gridDim.x * blockDim.x;
  for (; i < n; i += st) d[i] = (f16)s[i];
}

__global__ void k_scatter(const float* __restrict__ x, const int* __restrict__ idx,
                          f16* __restrict__ xpad, int total) {
  int i = blockIdx.x * blockDim.x + threadIdx.x;
  int st = gridDim.x * blockDim.x;
  int n = total * DD;
  for (; i < n; i += st) {
    int p = i >> 9;          // / DD
    int j = i & (DD - 1);
    xpad[(size_t)idx[p] * DD + j] = (f16)x[i];
  }
}

__global__ void k_inv(const int* __restrict__ idx, int* __restrict__ inv, int total) {
  int i = blockIdx.x * blockDim.x + threadIdx.x;
  if (i < total) inv[idx[i]] = i;
}

// ---------------- fp16 GEMM: C[m,n] = sum_k A[m,k]*Bw[n,k] + bias[n] ----------------
__global__ __launch_bounds__(256)
void k_gemm(const f16* __restrict__ A, const f16* __restrict__ Bw,
            const float* __restrict__ bias, f16* __restrict__ C,
            int N, int K, int Mvalid) {
  __shared__ __align__(16) f16 As[128 * 32];
  __shared__ __align__(16) f16 Bs[128 * 32];
  const int tid  = threadIdx.x;
  const int lane = tid & 63;
  const int wave = tid >> 6;
  const int m0 = blockIdx.y * 128;
  const int n0 = blockIdx.x * 128;
  const int mw = (wave >> 1) * 64;
  const int nw = (wave & 1) * 64;
  const int NT = K >> 5;
  const int c0 = tid * 2;

  float4 pa[2], pb[2];
  auto fetch = [&](int kt) {
#pragma unroll
    for (int i = 0; i < 2; ++i) {
      int c = c0 + i;
      int row = c >> 2, kc = c & 3;
      pa[i] = *(const float4*)&A [(size_t)(m0 + row) * K + kt * 32 + kc * 8];
      pb[i] = *(const float4*)&Bw[(size_t)(n0 + row) * K + kt * 32 + kc * 8];
    }
  };

  f32x4 acc[4][4] = {};
  fetch(0);
  for (int kt = 0; kt < NT; ++kt) {
    __syncthreads();
#pragma unroll
    for (int i = 0; i < 2; ++i) {
      int c = c0 + i;
      *(float4*)&As[c * 8] = pa[i];
      *(float4*)&Bs[c * 8] = pb[i];
    }
    __syncthreads();
    if (kt + 1 < NT) fetch(kt + 1);
    f16x8 af[4], bf[4];
#pragma unroll
    for (int i = 0; i < 4; ++i) {
      af[i] = *(const f16x8*)&As[(mw + i * 16 + (lane & 15)) * 32 + (lane >> 4) * 8];
      bf[i] = *(const f16x8*)&Bs[(nw + i * 16 + (lane & 15)) * 32 + (lane >> 4) * 8];
    }
#pragma unroll
    for (int i = 0; i < 4; ++i)
#pragma unroll
      for (int j = 0; j < 4; ++j)
        acc[i][j] = __builtin_amdgcn_mfma_f32_16x16x32_f16(af[i], bf[j], acc[i][j], 0, 0, 0);
  }

#pragma unroll
  for (int j = 0; j < 4; ++j) {
    int col = n0 + nw + j * 16 + (lane & 15);
    float bv = bias[col];
#pragma unroll
    for (int i = 0; i < 4; ++i) {
#pragma unroll
      for (int r = 0; r < 4; ++r) {
        int row = m0 + mw + i * 16 + (lane >> 4) * 4 + r;
        if (row < Mvalid) C[(size_t)row * N + col] = (f16)(acc[i][j][r] + bv);
      }
    }
  }
}

// ---------------- fence-free device barrier (packed flags, coalesced poll) ----------------
__device__ __forceinline__ void gbar(int* flags, int epoch) {
  __syncthreads();   // drains each wave's outstanding global stores (vmcnt 0) before s_barrier
  const int tid = threadIdx.x;
  if (tid == 0) ASTORE(&flags[blockIdx.x], epoch);
  if (tid < RWG) {
    while (ALOAD32(&flags[tid]) < epoch) __builtin_amdgcn_s_sleep(1);
  }
  __syncthreads();
}

// ---------------- persistent recurrence kernel ----------------
// 64 wgs x 512 thr. Phase A: wg = col-slice cs (32 cols); wave = (rt 0..3, kh 0..1):
// disjoint K-half h-load (no dup), partials for both ct tiles, LDS half-K reduction.
// Phase B: wave <-> (b=(wg&7)*8+wave, nh=wg>>3); thread owns dims d0=2*lane, d0+1.
// Role/unbind bases in LDS; h carried in registers; h/fg via LLC atomics only.
__global__ __launch_bounds__(512, 2)
void k_rec(const f16* __restrict__ Wh16, const float* __restrict__ bh,
           const f16* __restrict__ v16,  const f16* __restrict__ x2fg,
           f16* __restrict__ hfrag, float* __restrict__ fgbuf,
           f16* __restrict__ hs_out, float* __restrict__ out_packed,
           float* __restrict__ hn_out,
           const int* __restrict__ inv, const int* __restrict__ lgt,
           int* __restrict__ flags, int epoch0)
{
  __shared__ __align__(16) f16   Wlds[32 * 2 * 64 * 8];  // 64 KB [kk][ct][lane][8]
  __shared__ __align__(16) f16x4 Rq[32 * 64];            // 16 KB
  __shared__ __align__(16) f16x4 Uq[16 * 2 * 64];        // 16 KB
  __shared__ __align__(16) f32x4 pbuf[8][64];            // 8 KB: half-K partial tiles
  __shared__ __align__(16) float fbuf[8][128];           // 4 KB (wave-private rows)
  __shared__ __align__(16) float abuf[8][64];            // 2 KB (wave-private rows)

  const int tid  = threadIdx.x;
  const int lane = tid & 63;
  const int wave = tid >> 6;
  const int wg   = blockIdx.x;
  const int cs   = wg;                   // col-slice: cols cs*32 .. cs*32+32
  const int rt   = wave & 3;             // row tile 0..3
  const int kh   = wave >> 2;            // K-half 0/1
  const int nh   = wg >> 3;
  const int b    = ((wg & 7) << 3) + wave;
  const int cf   = nh * HD_;

  // stage full-K Wh slice (32 cols) into LDS in MFMA B-fragment layout
  for (int i = tid; i < 32 * 2 * 64; i += 512) {
    int kk = i >> 7;
    int nt = (i >> 6) & 1;
    int ln = i & 63;
    int col = cs * 32 + nt * 16 + (ln & 15);
    int kg  = kk * 32 + (ln >> 4) * 8;
    *(float4*)&Wlds[(size_t)i * 8] = *(const float4*)&Wh16[(size_t)col * HH + kg];
  }
  // role basis -> LDS
  for (int e = tid; e < 32 * 64; e += 512) {
    int i = e >> 6, role = e & 63;
    Rq[e] = *(const f16x4*)&v16[(size_t)role * H2 + nh * 256 + 4 * i];
  }
  // unbind basis -> LDS
  for (int e = tid; e < 16 * 2 * 64; e += 512) {
    int i = e >> 7, half = (e >> 6) & 1, l = e & 63;
    int r0 = 4 * i + 2 * half;
    const f16* u0 = &v16[(size_t)r0 * H2 + nh * 256 + 128 + 2 * l];
    const f16* u1 = &v16[(size_t)(r0 + 1) * H2 + nh * 256 + 128 + 2 * l];
    f16x4 tv; tv.x = u0[0]; tv.y = u0[1]; tv.z = u1[0]; tv.w = u1[1];
    Uq[e] = tv;
  }
  __syncthreads();

  const int d0 = cf + 2 * lane;
  const float2 bf2 = *(const float2*)&bh[d0];
  const float2 bg2 = *(const float2*)&bh[HH + d0];
  const int lb = lgt[b];
  float ho0 = 0.f, ho1 = 0.f;
  int ep = epoch0;
  const unsigned long long* hq = (const unsigned long long*)hfrag;

  for (int t = 0; t < TT; ++t) {
    const size_t row = (size_t)t * BB + b;
    // ---- prefetch phase-B inputs ----
    const f16* xr = x2fg + row * H2;
    f16x2 xf = *(const f16x2*)&xr[d0];
    f16x2 xg = *(const f16x2*)&xr[HH + d0];
    int   p  = inv[row];

    // ---------- phase A: K-half partials for both ct tiles ----------
    f32x4 acc0 = {0.f, 0.f, 0.f, 0.f}, acc1 = acc0;
    {
      unsigned long long hlo[16], hhi[16];
#pragma unroll
      for (int j = 0; j < 16; ++j) {
        int kk = kh * 16 + j;
        size_t qi = ((size_t)(kk * 4 + rt) * 64 + lane) * 2;
        hlo[j] = ALOAD64(&hq[qi]);
        hhi[j] = ALOAD64(&hq[qi + 1]);
      }
#pragma unroll
      for (int j = 0; j < 16; ++j) {
        int kk = kh * 16 + j;
        f16x8 af = __builtin_shufflevector(__builtin_bit_cast(f16x4, hlo[j]),
                                           __builtin_bit_cast(f16x4, hhi[j]),
                                           0, 1, 2, 3, 4, 5, 6, 7);
        f16x8 b0 = *(const f16x8*)&Wlds[((kk * 2 + 0) * 64 + lane) * 8];
        f16x8 b1 = *(const f16x8*)&Wlds[((kk * 2 + 1) * 64 + lane) * 8];
        acc0 = __builtin_amdgcn_mfma_f32_16x16x32_f16(af, b0, acc0, 0, 0, 0);
        acc1 = __builtin_amdgcn_mfma_f32_16x16x32_f16(af, b1, acc1, 0, 0, 0);
      }
    }
    // half-K reduction: wave (rt,kh) finalizes ct==kh; stores the other partial
    pbuf[wave][lane] = (kh == 0) ? acc1 : acc0;
    __syncthreads();
    {
      f32x4 acc = ((kh == 0) ? acc0 : acc1) + pbuf[wave ^ 4][lane];
      const int col = cs * 32 + kh * 16 + (lane & 15);
      const int r0  = rt * 16 + (lane >> 4) * 4;
#pragma unroll
      for (int r = 0; r < 4; ++r) ASTORE(&fgbuf[(size_t)(r0 + r) * H2 + col], acc[r]);
    }
    gbar(flags, ++ep);

    // ---------- phase B ----------
    float2 fv = __builtin_bit_cast(float2, ALOAD64((const unsigned long long*)&fgbuf[(size_t)b * H2 + d0]));
    float2 gv = __builtin_bit_cast(float2, ALOAD64((const unsigned long long*)&fgbuf[(size_t)b * H2 + HH + d0]));
    float f0 = fv.x + bf2.x + (float)xf.x;
    float f1 = fv.y + bf2.y + (float)xf.y;
    float g0 = gv.x + bg2.x + (float)xg.x;
    float g1 = gv.y + bg2.y + (float)xg.y;
    *(float2*)&fbuf[wave][2 * lane] = make_float2(f0, f1);
    float s = 0.f;
#pragma unroll
    for (int i = 0; i < 32; ++i) {
      float4 fvv = *(const float4*)&fbuf[wave][4 * i];
      f16x4 rv = Rq[i * 64 + lane];
      s = fmaf(fvv.x, (float)rv.x, s);
      s = fmaf(fvv.y, (float)rv.y, s);
      s = fmaf(fvv.z, (float)rv.z, s);
      s = fmaf(fvv.w, (float)rv.w, s);
    }
    float mx = s;
#pragma unroll
    for (int off = 32; off > 0; off >>= 1) mx = fmaxf(mx, __shfl_xor(mx, off));
    float e = expf(s - mx);
    float sum = e;
#pragma unroll
    for (int off = 32; off > 0; off >>= 1) sum += __shfl_xor(sum, off);
    abuf[wave][lane] = e / sum;
    float bd0 = 0.f, bd1 = 0.f;
#pragma unroll
    for (int i = 0; i < 16; ++i) {
      float4 av = *(const float4*)&abuf[wave][4 * i];
      f16x4 u01 = Uq[(i * 2 + 0) * 64 + lane];
      f16x4 u23 = Uq[(i * 2 + 1) * 64 + lane];
      bd0 = fmaf(av.x, (float)u01.x, bd0); bd1 = fmaf(av.x, (float)u01.y, bd1);
      bd0 = fmaf(av.y, (float)u01.z, bd0); bd1 = fmaf(av.y, (float)u01.w, bd1);
      bd0 = fmaf(av.z, (float)u23.x, bd0); bd1 = fmaf(av.z, (float)u23.y, bd1);
      bd0 = fmaf(av.w, (float)u23.z, bd0); bd1 = fmaf(av.w, (float)u23.w, bd1);
    }
    float gt0 = 1.f / (1.f + expf(-g0));
    float gt1 = 1.f / (1.f + expf(-g1));
    float hv0 = gt0 * tanhf(bd0) + (1.f - gt0) * ho0;
    float hv1 = gt1 * tanhf(bd1) + (1.f - gt1) * ho1;
    ho0 = hv0; ho1 = hv1;
    {
      const int k0 = d0;
      unsigned hp = (unsigned)__builtin_bit_cast(unsigned short, (f16)hv0)
                  | ((unsigned)__builtin_bit_cast(unsigned short, (f16)hv1) << 16);
      size_t ui = (((size_t)(k0 >> 5) * 4 + (b >> 4)) * 64
                   + ((b & 15) + (((k0 >> 3) & 3) << 4))) * 4 + ((k0 & 7) >> 1);
      ASTORE((unsigned*)hfrag + ui, hp);
    }
    gbar(flags, ++ep);

    // ---- deferred output writes: overlap with next iteration's phase A ----
    if (hs_out) {
      f16x2 hp2; hp2.x = (f16)ho0; hp2.y = (f16)ho1;
      *(f16x2*)&hs_out[row * HH + d0] = hp2;
    }
    if (out_packed && p >= 0) {
      *(float2*)&out_packed[(size_t)p * HH + d0] = make_float2(ho0, ho1);
    }
    if (lb == t + 1) {
      *(float2*)&hn_out[(size_t)b * HH + d0] = make_float2(ho0, ho1);
    }
  }
}

// ---------------- diagnostic probes (decompose per-step cost; written to scratch only) ----
__global__ __launch_bounds__(512, 2)
void k_probe_bar(int* __restrict__ flags, int iters) {
  int ep = 0;
  for (int t = 0; t < iters; ++t) {
    gbar(flags, ++ep);
    gbar(flags, ++ep);
  }
}

__global__ __launch_bounds__(512, 2)
void k_probe_ld(const f16* __restrict__ hfrag, float* __restrict__ fgbuf,
                f16* __restrict__ hsink, int* __restrict__ flags,
                float* __restrict__ sink, int iters) {
  const int tid = threadIdx.x, lane = tid & 63, wave = tid >> 6, wg = blockIdx.x;
  const int cs = wg, rt = wave & 3, kh = wave >> 2;
  const int nh = wg >> 3;
  const int b  = ((wg & 7) << 3) + wave;
  const int d0 = nh * HD_ + 2 * lane;
  const unsigned long long* hq = (const unsigned long long*)hfrag;
  int ep = 0;
  float accv = 1.f;
  for (int t = 0; t < iters; ++t) {
    // phase-A-like exchange: 32 uncached 8B loads + 4 scattered 4B stores
    unsigned long long sacc = 0;
#pragma unroll
    for (int j = 0; j < 16; ++j) {
      int kk = kh * 16 + j;
      size_t qi = ((size_t)(kk * 4 + rt) * 64 + lane) * 2;
      sacc += ALOAD64(&hq[qi]) + ALOAD64(&hq[qi + 1]);
    }
    accv += (float)(sacc & 0xFFFFu) * 1e-30f;
    const int col = cs * 32 + kh * 16 + (lane & 15);
    const int r0  = rt * 16 + (lane >> 4) * 4;
#pragma unroll
    for (int r = 0; r < 4; ++r) ASTORE(&fgbuf[(size_t)(r0 + r) * H2 + col], accv);
    gbar(flags, ++ep);
    // phase-B-like exchange: 2 uncached 8B loads + 1 packed u32 h store
    float2 fv = __builtin_bit_cast(float2, ALOAD64((const unsigned long long*)&fgbuf[(size_t)b * H2 + d0]));
    float2 gv = __builtin_bit_cast(float2, ALOAD64((const unsigned long long*)&fgbuf[(size_t)b * H2 + HH + d0]));
    accv += (fv.x + gv.y) * 1e-30f;
    const int k0 = d0;
    unsigned hp = __builtin_bit_cast(unsigned, accv);
    size_t ui = (((size_t)(k0 >> 5) * 4 + (b >> 4)) * 64
                 + ((b & 15) + (((k0 >> 3) & 3) << 4))) * 4 + ((k0 & 7) >> 1);
    ASTORE((unsigned*)hsink + ui, hp);
    gbar(flags, ++ep);
  }
  sink[(size_t)wg * 512 + tid] = accv;
}

// ---------------- host ----------------
extern "C" void kernel_launch(void* const* d_in, const int* in_sizes, int n_in,
                              void* d_out, int out_size, void* d_ws, size_t ws_size,
                              hipStream_t stream) {
  const float* x      = (const float*)d_in[0];
  const int*   idx    = (const int*)d_in[1];
  const int*   lgt    = (const int*)d_in[2];
  const float* basis0 = (const float*)d_in[3];
  const float* basis1 = (const float*)d_in[4];
  const float* Wx0 = (const float*)d_in[5];  const float* bx0 = (const float*)d_in[6];
  const float* Wh0 = (const float*)d_in[7];  const float* bh0 = (const float*)d_in[8];
  const float* Wv0 = (const float*)d_in[9];  const float* bv0 = (const float*)d_in[10];
  const float* Wx1 = (const float*)d_in[11]; const float* bx1 = (const float*)d_in[12];
  const float* Wh1 = (const float*)d_in[13]; const float* bh1 = (const float*)d_in[14];
  const float* Wv1 = (const float*)d_in[15]; const float* bv1 = (const float*)d_in[16];
  const int total = in_sizes[1];

  char* ws = (char*)d_ws;
  size_t off = 0;
  auto alloc = [&](size_t bytes) -> void* {
    void* p = (void*)(ws + off);
    off += (bytes + 255) & ~(size_t)255;
    return p;
  };

  int*   flags   = (int*)alloc(RWG * 4);
  int*   flagsB  = (int*)alloc(RWG * 4);
  int*   flagsC  = (int*)alloc(RWG * 4);
  float* sink    = (float*)alloc((size_t)RWG * 512 * 4);
  int*   inv     = (int*)alloc((size_t)MROWS * 4);
  f16*   xpad    = (f16*)alloc((size_t)MROWS * DD * 2);
  f16*   x2fg    = (f16*)alloc((size_t)MROWS * H2 * 2);
  f16*   hfrag   = (f16*)alloc((size_t)BB * HH * 2);
  float* fgbuf   = (float*)alloc((size_t)BB * H2 * 4);
  f16* Wx0h = (f16*)alloc((size_t)H2 * DD * 2);
  f16* Wh0h = (f16*)alloc((size_t)H2 * HH * 2);
  f16* Wv0h = (f16*)alloc((size_t)H2 * HH * 2);
  f16* Wx1h = (f16*)alloc((size_t)H2 * HH * 2);
  f16* Wh1h = (f16*)alloc((size_t)H2 * HH * 2);
  f16* Wv1h = (f16*)alloc((size_t)H2 * HH * 2);
  f16* bas0h = (f16*)alloc((size_t)128 * HH * 2);
  f16* bas1h = (f16*)alloc((size_t)128 * HH * 2);
  f16* v0h = (f16*)alloc((size_t)NR_ * H2 * 2);
  f16* v1h = (f16*)alloc((size_t)NR_ * H2 * 2);

  float* out = (float*)d_out;
  float* hn0 = out + (size_t)total * HH;
  float* hn1 = hn0 + (size_t)BB * HH;
  f16* hs0 = (f16*)d_out;   // layer-0 hidden stash (64 MB), dead before layer-1 output

  (void)hipMemsetAsync(flags, 0, RWG * 4, stream);
  (void)hipMemsetAsync(flagsB, 0, RWG * 4, stream);
  (void)hipMemsetAsync(flagsC, 0, RWG * 4, stream);
  (void)hipMemsetAsync(inv, 0xFF, (size_t)MROWS * 4, stream);
  (void)hipMemsetAsync(xpad, 0, (size_t)MROWS * DD * 2, stream);
  (void)hipMemsetAsync(bas0h, 0, (size_t)128 * HH * 2, stream);
  (void)hipMemsetAsync(bas1h, 0, (size_t)128 * HH * 2, stream);
  (void)hipMemsetAsync(hfrag, 0, (size_t)BB * HH * 2, stream);

  k_cvt<<<512, 256, 0, stream>>>(Wx0, Wx0h, H2 * DD);
  k_cvt<<<512, 256, 0, stream>>>(Wh0, Wh0h, H2 * HH);
  k_cvt<<<512, 256, 0, stream>>>(Wv0, Wv0h, H2 * HH);
  k_cvt<<<512, 256, 0, stream>>>(Wx1, Wx1h, H2 * HH);
  k_cvt<<<512, 256, 0, stream>>>(Wh1, Wh1h, H2 * HH);
  k_cvt<<<512, 256, 0, stream>>>(Wv1, Wv1h, H2 * HH);
  k_cvt<<<64, 256, 0, stream>>>(basis0, bas0h, NR_ * HH);
  k_cvt<<<64, 256, 0, stream>>>(basis1, bas1h, NR_ * HH);
  k_scatter<<<2048, 256, 0, stream>>>(x, idx, xpad, total);
  k_inv<<<(total + 255) / 256, 256, 0, stream>>>(idx, inv, total);

  dim3 gv(16, 1);
  k_gemm<<<gv, 256, 0, stream>>>(bas0h, Wv0h, bv0, v0h, H2, HH, NR_);
  k_gemm<<<gv, 256, 0, stream>>>(bas1h, Wv1h, bv1, v1h, H2, HH, NR_);

  dim3 gx(H2 / 128, MROWS / 128);
  k_gemm<<<gx, 256, 0, stream>>>(xpad, Wx0h, bx0, x2fg, H2, DD, MROWS);

  k_rec<<<RWG, 512, 0, stream>>>(Wh0h, bh0, v0h, x2fg, hfrag, fgbuf,
                                 hs0, nullptr, hn0, inv, lgt, flags, 0);

  (void)hipMemsetAsync(hfrag, 0, (size_t)BB * HH * 2, stream);

  k_gemm<<<gx, 256, 0, stream>>>(hs0, Wx1h, bx1, x2fg, H2, HH, MROWS);

  k_rec<<<RWG, 512, 0, stream>>>(Wh1h, bh1, v1h, x2fg, hfrag, fgbuf,
                                 nullptr, out, hn1, inv, lgt, flags, 2 * TT);

  // diagnostic probes (scratch-only writes; 128 steps each)
  k_probe_bar<<<RWG, 512, 0, stream>>>(flagsB, 128);
  k_probe_ld<<<RWG, 512, 0, stream>>>(hfrag, fgbuf, hfrag, flagsC, sink, 128);
}

// Round 8
// 11524.305 us; speedup vs baseline: 6.5076x; 1.2526x over previous
//
#include <hip/hip_runtime.h>

typedef _Float16 f16;
typedef _Float16 f16x2 __attribute__((ext_vector_type(2)));
typedef _Float16 f16x4 __attribute__((ext_vector_type(4)));
typedef _Float16 f16x8 __attribute__((ext_vector_type(8)));
typedef float    f32x4 __attribute__((ext_vector_type(4)));

#define TT   512
#define BB   64
#define DD   512
#define HH   1024
#define H2   2048
#define NR_  64
#define NH_  8
#define HD_  128
#define MROWS (TT*BB)      // 32768
#define RWG  64            // recurrence workgroups

#define ALOAD32(p)   __hip_atomic_load((p),  __ATOMIC_RELAXED, __HIP_MEMORY_SCOPE_AGENT)
#define ALOAD64(p)   __hip_atomic_load((p),  __ATOMIC_RELAXED, __HIP_MEMORY_SCOPE_AGENT)
#define ASTORE(p,v)  __hip_atomic_store((p), (v), __ATOMIC_RELAXED, __HIP_MEMORY_SCOPE_AGENT)

// ---------------- prep kernels ----------------
__global__ void k_cvt(const float* __restrict__ s, f16* __restrict__ d, int n) {
  int i = blockIdx.x * blockDim.x + threadIdx.x;
  int st = gridDim.x * blockDim.x;
  for (; i < n; i += st) d[i] = (f16)s[i];
}

__global__ void k_scatter(const float* __restrict__ x, const int* __restrict__ idx,
                          f16* __restrict__ xpad, int total) {
  int i = blockIdx.x * blockDim.x + threadIdx.x;
  int st = gridDim.x * blockDim.x;
  int n = total * DD;
  for (; i < n; i += st) {
    int p = i >> 9;          // / DD
    int j = i & (DD - 1);
    xpad[(size_t)idx[p] * DD + j] = (f16)x[i];
  }
}

__global__ void k_inv(const int* __restrict__ idx, int* __restrict__ inv, int total) {
  int i = blockIdx.x * blockDim.x + threadIdx.x;
  if (i < total) inv[idx[i]] = i;
}

// ---------------- fp16 GEMM: C[m,n] = sum_k A[m,k]*Bw[n,k] + bias[n] ----------------
__global__ __launch_bounds__(256)
void k_gemm(const f16* __restrict__ A, const f16* __restrict__ Bw,
            const float* __restrict__ bias, f16* __restrict__ C,
            int N, int K, int Mvalid) {
  __shared__ __align__(16) f16 As[128 * 32];
  __shared__ __align__(16) f16 Bs[128 * 32];
  const int tid  = threadIdx.x;
  const int lane = tid & 63;
  const int wave = tid >> 6;
  const int m0 = blockIdx.y * 128;
  const int n0 = blockIdx.x * 128;
  const int mw = (wave >> 1) * 64;
  const int nw = (wave & 1) * 64;
  const int NT = K >> 5;
  const int c0 = tid * 2;

  float4 pa[2], pb[2];
  auto fetch = [&](int kt) {
#pragma unroll
    for (int i = 0; i < 2; ++i) {
      int c = c0 + i;
      int row = c >> 2, kc = c & 3;
      pa[i] = *(const float4*)&A [(size_t)(m0 + row) * K + kt * 32 + kc * 8];
      pb[i] = *(const float4*)&Bw[(size_t)(n0 + row) * K + kt * 32 + kc * 8];
    }
  };

  f32x4 acc[4][4] = {};
  fetch(0);
  for (int kt = 0; kt < NT; ++kt) {
    __syncthreads();
#pragma unroll
    for (int i = 0; i < 2; ++i) {
      int c = c0 + i;
      *(float4*)&As[c * 8] = pa[i];
      *(float4*)&Bs[c * 8] = pb[i];
    }
    __syncthreads();
    if (kt + 1 < NT) fetch(kt + 1);
    f16x8 af[4], bf[4];
#pragma unroll
    for (int i = 0; i < 4; ++i) {
      af[i] = *(const f16x8*)&As[(mw + i * 16 + (lane & 15)) * 32 + (lane >> 4) * 8];
      bf[i] = *(const f16x8*)&Bs[(nw + i * 16 + (lane & 15)) * 32 + (lane >> 4) * 8];
    }
#pragma unroll
    for (int i = 0; i < 4; ++i)
#pragma unroll
      for (int j = 0; j < 4; ++j)
        acc[i][j] = __builtin_amdgcn_mfma_f32_16x16x32_f16(af[i], bf[j], acc[i][j], 0, 0, 0);
  }

#pragma unroll
  for (int j = 0; j < 4; ++j) {
    int col = n0 + nw + j * 16 + (lane & 15);
    float bv = bias[col];
#pragma unroll
    for (int i = 0; i < 4; ++i) {
#pragma unroll
      for (int r = 0; r < 4; ++r) {
        int row = m0 + mw + i * 16 + (lane >> 4) * 4 + r;
        if (row < Mvalid) C[(size_t)row * N + col] = (f16)(acc[i][j][r] + bv);
      }
    }
  }
}

// ---------------- fence-free device barrier (packed flags, coalesced poll) ----------------
__device__ __forceinline__ void gbar(int* flags, int epoch) {
  __syncthreads();   // drains each wave's outstanding global stores (vmcnt 0) before s_barrier
  const int tid = threadIdx.x;
  if (tid == 0) ASTORE(&flags[blockIdx.x], epoch);
  if (tid < RWG) {
    while (ALOAD32(&flags[tid]) < epoch) __builtin_amdgcn_s_sleep(1);
  }
  __syncthreads();
}

// ---------------- persistent recurrence kernel ----------------
// 64 wgs x 512 thr. Phase A: wg = col-slice cs (32 cols); wave = (rt 0..3, kh 0..1):
// disjoint K-half h-load via coalesced 16B sc0/sc1 (LLC-coherent) vector loads,
// partials for both ct tiles, LDS half-K reduction.
// Phase B: wave <-> (b=(wg&7)*8+wave, nh=wg>>3); thread owns dims d0=2*lane, d0+1.
// Role/unbind bases in LDS; h carried in registers; h/fg stores via LLC atomics.
__global__ __launch_bounds__(512, 2)
void k_rec(const f16* __restrict__ Wh16, const float* __restrict__ bh,
           const f16* __restrict__ v16,  const f16* __restrict__ x2fg,
           f16* __restrict__ hfrag, float* __restrict__ fgbuf,
           f16* __restrict__ hs_out, float* __restrict__ out_packed,
           float* __restrict__ hn_out,
           const int* __restrict__ inv, const int* __restrict__ lgt,
           int* __restrict__ flags, int epoch0)
{
  __shared__ __align__(16) f16   Wlds[32 * 2 * 64 * 8];  // 64 KB [kk][ct][lane][8]
  __shared__ __align__(16) f16x4 Rq[32 * 64];            // 16 KB
  __shared__ __align__(16) f16x4 Uq[16 * 2 * 64];        // 16 KB
  __shared__ __align__(16) f32x4 pbuf[8][64];            // 8 KB: half-K partial tiles
  __shared__ __align__(16) float fbuf[8][128];           // 4 KB (wave-private rows)
  __shared__ __align__(16) float abuf[8][64];            // 2 KB (wave-private rows)

  const int tid  = threadIdx.x;
  const int lane = tid & 63;
  const int wave = tid >> 6;
  const int wg   = blockIdx.x;
  const int cs   = wg;                   // col-slice: cols cs*32 .. cs*32+32
  const int rt   = wave & 3;             // row tile 0..3
  const int kh   = wave >> 2;            // K-half 0/1
  const int nh   = wg >> 3;
  const int b    = ((wg & 7) << 3) + wave;
  const int cf   = nh * HD_;

  // stage full-K Wh slice (32 cols) into LDS in MFMA B-fragment layout
  for (int i = tid; i < 32 * 2 * 64; i += 512) {
    int kk = i >> 7;
    int nt = (i >> 6) & 1;
    int ln = i & 63;
    int col = cs * 32 + nt * 16 + (ln & 15);
    int kg  = kk * 32 + (ln >> 4) * 8;
    *(float4*)&Wlds[(size_t)i * 8] = *(const float4*)&Wh16[(size_t)col * HH + kg];
  }
  // role basis -> LDS
  for (int e = tid; e < 32 * 64; e += 512) {
    int i = e >> 6, role = e & 63;
    Rq[e] = *(const f16x4*)&v16[(size_t)role * H2 + nh * 256 + 4 * i];
  }
  // unbind basis -> LDS
  for (int e = tid; e < 16 * 2 * 64; e += 512) {
    int i = e >> 7, half = (e >> 6) & 1, l = e & 63;
    int r0 = 4 * i + 2 * half;
    const f16* u0 = &v16[(size_t)r0 * H2 + nh * 256 + 128 + 2 * l];
    const f16* u1 = &v16[(size_t)(r0 + 1) * H2 + nh * 256 + 128 + 2 * l];
    f16x4 tv; tv.x = u0[0]; tv.y = u0[1]; tv.z = u1[0]; tv.w = u1[1];
    Uq[e] = tv;
  }
  __syncthreads();

  const int d0 = cf + 2 * lane;
  const float2 bf2 = *(const float2*)&bh[d0];
  const float2 bg2 = *(const float2*)&bh[HH + d0];
  const int lb = lgt[b];
  float ho0 = 0.f, ho1 = 0.f;
  int ep = epoch0;
  // per-wave h fragment base: bytes(kk,lane) = ((kk*4+rt)*64+lane)*16, kk = kh*16+j
  const char* hb0 = (const char*)hfrag + (((size_t)kh * 64 + rt) * 64 + lane) * 16;
  const char* fp  = (const char*)fgbuf + (((size_t)b * H2) + d0) * 4;
  const char* gp  = fp + (size_t)HH * 4;

  for (int t = 0; t < TT; ++t) {
    const size_t row = (size_t)t * BB + b;
    // ---- prefetch phase-B inputs (cached; consumed after barrier 1) ----
    const f16* xr = x2fg + row * H2;
    f16x2 xf = *(const f16x2*)&xr[d0];
    f16x2 xg = *(const f16x2*)&xr[HH + d0];
    int   p  = inv[row];

    // ---------- phase A: K-half partials for both ct tiles ----------
    f32x4 acc0 = {0.f, 0.f, 0.f, 0.f}, acc1 = acc0;
    {
      float4 hb[16];
#pragma unroll
      for (int j = 0; j < 16; ++j) {
        asm volatile("global_load_dwordx4 %0, %1, off sc0 sc1"
                     : "=v"(hb[j]) : "v"(hb0 + (size_t)j * 4096));
      }
      asm volatile("s_waitcnt vmcnt(0)" ::: "memory");
      __builtin_amdgcn_sched_barrier(0);
#pragma unroll
      for (int j = 0; j < 16; ++j) {
        int kk = kh * 16 + j;
        f16x8 af = __builtin_bit_cast(f16x8, hb[j]);
        f16x8 b0 = *(const f16x8*)&Wlds[((kk * 2 + 0) * 64 + lane) * 8];
        f16x8 b1 = *(const f16x8*)&Wlds[((kk * 2 + 1) * 64 + lane) * 8];
        acc0 = __builtin_amdgcn_mfma_f32_16x16x32_f16(af, b0, acc0, 0, 0, 0);
        acc1 = __builtin_amdgcn_mfma_f32_16x16x32_f16(af, b1, acc1, 0, 0, 0);
      }
    }
    // half-K reduction: wave (rt,kh) finalizes ct==kh; stores the other partial
    pbuf[wave][lane] = (kh == 0) ? acc1 : acc0;
    __syncthreads();
    {
      f32x4 acc = ((kh == 0) ? acc0 : acc1) + pbuf[wave ^ 4][lane];
      const int col = cs * 32 + kh * 16 + (lane & 15);
      const int r0  = rt * 16 + (lane >> 4) * 4;
#pragma unroll
      for (int r = 0; r < 4; ++r) ASTORE(&fgbuf[(size_t)(r0 + r) * H2 + col], acc[r]);
    }
    gbar(flags, ++ep);

    // ---------- phase B ----------
    float2 fv, gv;
    asm volatile("global_load_dwordx2 %0, %1, off sc0 sc1" : "=v"(fv) : "v"(fp));
    asm volatile("global_load_dwordx2 %0, %1, off sc0 sc1" : "=v"(gv) : "v"(gp));
    asm volatile("s_waitcnt vmcnt(0)" ::: "memory");
    __builtin_amdgcn_sched_barrier(0);
    float f0 = fv.x + bf2.x + (float)xf.x;
    float f1 = fv.y + bf2.y + (float)xf.y;
    float g0 = gv.x + bg2.x + (float)xg.x;
    float g1 = gv.y + bg2.y + (float)xg.y;
    *(float2*)&fbuf[wave][2 * lane] = make_float2(f0, f1);
    float s = 0.f;
#pragma unroll
    for (int i = 0; i < 32; ++i) {
      float4 fvv = *(const float4*)&fbuf[wave][4 * i];
      f16x4 rv = Rq[i * 64 + lane];
      s = fmaf(fvv.x, (float)rv.x, s);
      s = fmaf(fvv.y, (float)rv.y, s);
      s = fmaf(fvv.z, (float)rv.z, s);
      s = fmaf(fvv.w, (float)rv.w, s);
    }
    float mx = s;
#pragma unroll
    for (int off = 32; off > 0; off >>= 1) mx = fmaxf(mx, __shfl_xor(mx, off));
    float e = expf(s - mx);
    float sum = e;
#pragma unroll
    for (int off = 32; off > 0; off >>= 1) sum += __shfl_xor(sum, off);
    abuf[wave][lane] = e / sum;
    float bd0 = 0.f, bd1 = 0.f;
#pragma unroll
    for (int i = 0; i < 16; ++i) {
      float4 av = *(const float4*)&abuf[wave][4 * i];
      f16x4 u01 = Uq[(i * 2 + 0) * 64 + lane];
      f16x4 u23 = Uq[(i * 2 + 1) * 64 + lane];
      bd0 = fmaf(av.x, (float)u01.x, bd0); bd1 = fmaf(av.x, (float)u01.y, bd1);
      bd0 = fmaf(av.y, (float)u01.z, bd0); bd1 = fmaf(av.y, (float)u01.w, bd1);
      bd0 = fmaf(av.z, (float)u23.x, bd0); bd1 = fmaf(av.z, (float)u23.y, bd1);
      bd0 = fmaf(av.w, (float)u23.z, bd0); bd1 = fmaf(av.w, (float)u23.w, bd1);
    }
    float gt0 = 1.f / (1.f + expf(-g0));
    float gt1 = 1.f / (1.f + expf(-g1));
    float hv0 = gt0 * tanhf(bd0) + (1.f - gt0) * ho0;
    float hv1 = gt1 * tanhf(bd1) + (1.f - gt1) * ho1;
    ho0 = hv0; ho1 = hv1;
    {
      const int k0 = d0;
      unsigned hp = (unsigned)__builtin_bit_cast(unsigned short, (f16)hv0)
                  | ((unsigned)__builtin_bit_cast(unsigned short, (f16)hv1) << 16);
      size_t ui = (((size_t)(k0 >> 5) * 4 + (b >> 4)) * 64
                   + ((b & 15) + (((k0 >> 3) & 3) << 4))) * 4 + ((k0 & 7) >> 1);
      ASTORE((unsigned*)hfrag + ui, hp);
    }
    gbar(flags, ++ep);

    // ---- deferred output writes: overlap with next iteration's phase A ----
    if (hs_out) {
      f16x2 hp2; hp2.x = (f16)ho0; hp2.y = (f16)ho1;
      *(f16x2*)&hs_out[row * HH + d0] = hp2;
    }
    if (out_packed && p >= 0) {
      *(float2*)&out_packed[(size_t)p * HH + d0] = make_float2(ho0, ho1);
    }
    if (lb == t + 1) {
      *(float2*)&hn_out[(size_t)b * HH + d0] = make_float2(ho0, ho1);
    }
  }
}

// ---------------- host ----------------
extern "C" void kernel_launch(void* const* d_in, const int* in_sizes, int n_in,
                              void* d_out, int out_size, void* d_ws, size_t ws_size,
                              hipStream_t stream) {
  const float* x      = (const float*)d_in[0];
  const int*   idx    = (const int*)d_in[1];
  const int*   lgt    = (const int*)d_in[2];
  const float* basis0 = (const float*)d_in[3];
  const float* basis1 = (const float*)d_in[4];
  const float* Wx0 = (const float*)d_in[5];  const float* bx0 = (const float*)d_in[6];
  const float* Wh0 = (const float*)d_in[7];  const float* bh0 = (const float*)d_in[8];
  const float* Wv0 = (const float*)d_in[9];  const float* bv0 = (const float*)d_in[10];
  const float* Wx1 = (const float*)d_in[11]; const float* bx1 = (const float*)d_in[12];
  const float* Wh1 = (const float*)d_in[13]; const float* bh1 = (const float*)d_in[14];
  const float* Wv1 = (const float*)d_in[15]; const float* bv1 = (const float*)d_in[16];
  const int total = in_sizes[1];

  char* ws = (char*)d_ws;
  size_t off = 0;
  auto alloc = [&](size_t bytes) -> void* {
    void* p = (void*)(ws + off);
    off += (bytes + 255) & ~(size_t)255;
    return p;
  };

  int*   flags   = (int*)alloc(RWG * 4);
  int*   inv     = (int*)alloc((size_t)MROWS * 4);
  f16*   xpad    = (f16*)alloc((size_t)MROWS * DD * 2);
  f16*   x2fg    = (f16*)alloc((size_t)MROWS * H2 * 2);
  f16*   hfrag   = (f16*)alloc((size_t)BB * HH * 2);
  float* fgbuf   = (float*)alloc((size_t)BB * H2 * 4);
  f16* Wx0h = (f16*)alloc((size_t)H2 * DD * 2);
  f16* Wh0h = (f16*)alloc((size_t)H2 * HH * 2);
  f16* Wv0h = (f16*)alloc((size_t)H2 * HH * 2);
  f16* Wx1h = (f16*)alloc((size_t)H2 * HH * 2);
  f16* Wh1h = (f16*)alloc((size_t)H2 * HH * 2);
  f16* Wv1h = (f16*)alloc((size_t)H2 * HH * 2);
  f16* bas0h = (f16*)alloc((size_t)128 * HH * 2);
  f16* bas1h = (f16*)alloc((size_t)128 * HH * 2);
  f16* v0h = (f16*)alloc((size_t)NR_ * H2 * 2);
  f16* v1h = (f16*)alloc((size_t)NR_ * H2 * 2);

  float* out = (float*)d_out;
  float* hn0 = out + (size_t)total * HH;
  float* hn1 = hn0 + (size_t)BB * HH;
  f16* hs0 = (f16*)d_out;   // layer-0 hidden stash (64 MB), dead before layer-1 output

  (void)hipMemsetAsync(flags, 0, RWG * 4, stream);
  (void)hipMemsetAsync(inv, 0xFF, (size_t)MROWS * 4, stream);
  (void)hipMemsetAsync(xpad, 0, (size_t)MROWS * DD * 2, stream);
  (void)hipMemsetAsync(bas0h, 0, (size_t)128 * HH * 2, stream);
  (void)hipMemsetAsync(bas1h, 0, (size_t)128 * HH * 2, stream);
  (void)hipMemsetAsync(hfrag, 0, (size_t)BB * HH * 2, stream);

  k_cvt<<<512, 256, 0, stream>>>(Wx0, Wx0h, H2 * DD);
  k_cvt<<<512, 256, 0, stream>>>(Wh0, Wh0h, H2 * HH);
  k_cvt<<<512, 256, 0, stream>>>(Wv0, Wv0h, H2 * HH);
  k_cvt<<<512, 256, 0, stream>>>(Wx1, Wx1h, H2 * HH);
  k_cvt<<<512, 256, 0, stream>>>(Wh1, Wh1h, H2 * HH);
  k_cvt<<<512, 256, 0, stream>>>(Wv1, Wv1h, H2 * HH);
  k_cvt<<<64, 256, 0, stream>>>(basis0, bas0h, NR_ * HH);
  k_cvt<<<64, 256, 0, stream>>>(basis1, bas1h, NR_ * HH);
  k_scatter<<<2048, 256, 0, stream>>>(x, idx, xpad, total);
  k_inv<<<(total + 255) / 256, 256, 0, stream>>>(idx, inv, total);

  dim3 gv(16, 1);
  k_gemm<<<gv, 256, 0, stream>>>(bas0h, Wv0h, bv0, v0h, H2, HH, NR_);
  k_gemm<<<gv, 256, 0, stream>>>(bas1h, Wv1h, bv1, v1h, H2, HH, NR_);

  dim3 gx(H2 / 128, MROWS / 128);
  k_gemm<<<gx, 256, 0, stream>>>(xpad, Wx0h, bx0, x2fg, H2, DD, MROWS);

  k_rec<<<RWG, 512, 0, stream>>>(Wh0h, bh0, v0h, x2fg, hfrag, fgbuf,
                                 hs0, nullptr, hn0, inv, lgt, flags, 0);

  (void)hipMemsetAsync(hfrag, 0, (size_t)BB * HH * 2, stream);

  k_gemm<<<gx, 256, 0, stream>>>(hs0, Wx1h, bx1, x2fg, H2, HH, MROWS);

  k_rec<<<RWG, 512, 0, stream>>>(Wh1h, bh1, v1h, x2fg, hfrag, fgbuf,
                                 nullptr, out, hn1, inv, lgt, flags, 2 * TT);
}